// Round 1
// baseline (3236.092 us; speedup 1.0000x reference)
//
#include <hip/hip_runtime.h>
#include <hip/hip_bf16.h>

#define NB 2
#define NT 2048
#define ND 1024
#define NHEADS 16
#define NKVH 4
#define HDIM 64
#define QKVD 1536   // (NHEADS + 2*NKVH) * HDIM

typedef __attribute__((ext_vector_type(8))) short short8;
typedef __attribute__((ext_vector_type(4))) float floatx4;

__device__ __forceinline__ unsigned short f2bf(float f) {
  union { float f; unsigned int u; } cv; cv.f = f;
  unsigned int u = cv.u;
  u += 0x7fffu + ((u >> 16) & 1u);   // round-to-nearest-even
  return (unsigned short)(u >> 16);
}

// ---------------------------------------------------------------- converts
__global__ __launch_bounds__(256) void cvt_bf16(const float* __restrict__ in,
                                                unsigned short* __restrict__ out,
                                                int n4) {
  int i = blockIdx.x * 256 + threadIdx.x;
  if (i < n4) {
    float4 v = ((const float4*)in)[i];
    ushort4 o;
    o.x = f2bf(v.x); o.y = f2bf(v.y); o.z = f2bf(v.z); o.w = f2bf(v.w);
    ((ushort4*)out)[i] = o;
  }
}

// ------------------------------------------------- bf16 MFMA GEMM: C = A * B^T
// A: [M][K] bf16 row-major, Bm: [N][K] bf16 row-major, C: [M][N] fp32
// Block = 256 threads (4 waves), tile 64x64, BK=32.
__global__ __launch_bounds__(256) void gemm_bf16_nt(
    const unsigned short* __restrict__ A,
    const unsigned short* __restrict__ Bm,
    float* __restrict__ C, int M, int N, int K)
{
  __shared__ __align__(16) short As[64][40];  // +8 pad: 80B stride, 16B aligned
  __shared__ __align__(16) short Bs[64][40];

  const int tid  = threadIdx.x;
  const int wid  = tid >> 6;
  const int lane = tid & 63;
  const int quad = lane >> 4;
  const int l16  = lane & 15;
  const int m0 = blockIdx.x * 64;
  const int n0 = blockIdx.y * 64;

  // staging: each thread loads one 16B chunk of A and of B per BK step
  const int srow   = tid >> 2;        // 0..63
  const int schunk = (tid & 3) * 8;   // 0,8,16,24

  const unsigned short* ag = A  + (size_t)(m0 + srow) * K + schunk;
  const unsigned short* bg = Bm + (size_t)(n0 + srow) * K + schunk;

  floatx4 acc[4] = {};

  for (int k0 = 0; k0 < K; k0 += 32) {
    short8 av = *(const short8*)(ag + k0);
    short8 bv = *(const short8*)(bg + k0);
    *(short8*)&As[srow][schunk] = av;
    *(short8*)&Bs[srow][schunk] = bv;
    __syncthreads();

    short8 af = *(const short8*)&As[wid * 16 + l16][quad * 8];
#pragma unroll
    for (int nt = 0; nt < 4; nt++) {
      short8 bf = *(const short8*)&Bs[nt * 16 + l16][quad * 8];
      acc[nt] = __builtin_amdgcn_mfma_f32_16x16x32_bf16(af, bf, acc[nt], 0, 0, 0);
    }
    __syncthreads();
  }

#pragma unroll
  for (int nt = 0; nt < 4; nt++) {
#pragma unroll
    for (int r = 0; r < 4; r++) {
      int m = m0 + wid * 16 + quad * 4 + r;   // C/D: row = quad*4 + reg
      int n = n0 + nt * 16 + l16;             // C/D: col = lane & 15
      C[(size_t)m * N + n] = acc[nt][r];
    }
  }
}

// ------------------------------------------- RoPE(first 16 dims) + head scales
// qkv fp32 in-place. Grid: (NT, 5, NB), block 256 = 4 heads x 64 dims.
__global__ __launch_bounds__(256) void rope_scale(
    float* __restrict__ qkv,
    const float* __restrict__ cosT, const float* __restrict__ sinT,
    const float* __restrict__ q_scale, const float* __restrict__ k_scale)
{
  const int t  = blockIdx.x;
  const int b  = blockIdx.z;
  const int hh = blockIdx.y * 4 + (threadIdx.x >> 6);  // 0..19 (16 q + 4 k heads)
  const int d  = threadIdx.x & 63;

  float scale; int off;
  if (hh < NHEADS) { scale = q_scale[hh];          off = hh * HDIM; }
  else             { scale = k_scale[hh - NHEADS]; off = NHEADS * HDIM + (hh - NHEADS) * HDIM; }

  float* row = qkv + ((size_t)(b * NT + t)) * QKVD + off;
  if (d < 8) {
    float x1 = row[d], x2 = row[d + 8];
    float c = cosT[t * 8 + d], s = sinT[t * 8 + d];
    row[d]     = (x1 * c - x2 * s) * scale;
    row[d + 8] = (x1 * s + x2 * c) * scale;
  } else if (d >= 16) {
    row[d] *= scale;
  }
}

// --------------------------------------------------- attention, one (b,h,t) row
// fp32 scores in LDS, two-pass softmax, PV, then v-orthogonalization epilogue.
__global__ __launch_bounds__(256) void attn(
    const float* __restrict__ qkv,          // roped/scaled, [B][T][1536]
    unsigned short* __restrict__ aob)       // bf16 [B][T][1024]
{
  const int t = blockIdx.x, h = blockIdx.y, b = blockIdx.z;
  const int kv = h >> 2;                    // groups = 4
  const int tid = threadIdx.x;
  const int wid = tid >> 6, lane = tid & 63;

  __shared__ float sc[NT];
  __shared__ float qs[HDIM];
  __shared__ float op[4][HDIM];
  __shared__ float red[8];

  const float* qrow = qkv + ((size_t)(b * NT + t)) * QKVD + h * HDIM;
  if (tid < HDIM) qs[tid] = qrow[tid];
  __syncthreads();

  // ---- pass 1: scores
  const float* kbase = qkv + (size_t)b * NT * QKVD + NHEADS * HDIM + kv * HDIM;
  float mloc = -INFINITY;
  for (int j = tid; j <= t; j += 256) {
    const float4* kr = (const float4*)(kbase + (size_t)j * QKVD);
    const float4* q4 = (const float4*)qs;
    float s = 0.f;
#pragma unroll
    for (int c = 0; c < 16; c++) {
      float4 kk = kr[c]; float4 qq = q4[c];
      s += kk.x * qq.x + kk.y * qq.y + kk.z * qq.z + kk.w * qq.w;
    }
    s *= 0.125f;      // HD^-0.5
    sc[j] = s;
    mloc = fmaxf(mloc, s);
  }
#pragma unroll
  for (int off = 32; off; off >>= 1) mloc = fmaxf(mloc, __shfl_xor(mloc, off));
  if (lane == 0) red[wid] = mloc;
  __syncthreads();
  const float mx = fmaxf(fmaxf(red[0], red[1]), fmaxf(red[2], red[3]));

  float sloc = 0.f;
  for (int j = tid; j <= t; j += 256) {
    float e = __expf(sc[j] - mx);
    sc[j] = e;
    sloc += e;
  }
#pragma unroll
  for (int off = 32; off; off >>= 1) sloc += __shfl_xor(sloc, off);
  if (lane == 0) red[4 + wid] = sloc;
  __syncthreads();
  const float inv = 1.f / (red[4] + red[5] + red[6] + red[7]);

  // ---- pass 2: PV (lanes = d, 4 j-partitions)
  const int d = tid & 63, part = tid >> 6;
  const float* vbase = qkv + (size_t)b * NT * QKVD + (NHEADS + NKVH) * HDIM + kv * HDIM + d;
  float o = 0.f;
  for (int j = part; j <= t; j += 4) o += sc[j] * vbase[(size_t)j * QKVD];
  op[part][d] = o;
  __syncthreads();

  if (tid < 64) {
    float oa = (op[0][d] + op[1][d] + op[2][d] + op[3][d]) * inv;
    float vd = vbase[(size_t)t * QKVD];     // v at the query's own time index
    float dot = oa * vd, vv = vd * vd;
#pragma unroll
    for (int off = 32; off; off >>= 1) {
      dot += __shfl_xor(dot, off);
      vv  += __shfl_xor(vv, off);
    }
    float oo = oa - (dot / fmaxf(vv, 1e-8f)) * vd;
    aob[((size_t)(b * NT + t)) * (NHEADS * HDIM) + h * HDIM + d] = f2bf(oo);
  }
}

// ---------------------------------------------------------------------- launch
extern "C" void kernel_launch(void* const* d_in, const int* in_sizes, int n_in,
                              void* d_out, int out_size, void* d_ws, size_t ws_size,
                              hipStream_t stream) {
  const float* x       = (const float*)d_in[0];
  const float* cosT    = (const float*)d_in[1];
  const float* sinT    = (const float*)d_in[2];
  // d_in[3] attn_mask: unused (causal mask is structural)
  const float* w_qkv   = (const float*)d_in[4];
  const float* w_out   = (const float*)d_in[5];
  const float* q_scale = (const float*)d_in[6];
  const float* k_scale = (const float*)d_in[7];
  float* out = (float*)d_out;

  char* ws = (char*)d_ws;
  unsigned short* xb    = (unsigned short*)ws;                       // 8 MB
  unsigned short* wqkvb = xb + (size_t)NB * NT * ND;                 // 3 MB
  unsigned short* woutb = wqkvb + (size_t)QKVD * ND;                 // 2 MB
  float* qkv            = (float*)(woutb + (size_t)ND * ND);         // 25 MB fp32
  unsigned short* aob   = (unsigned short*)(qkv + (size_t)NB * NT * QKVD); // 8 MB

  // 1) fp32 -> bf16 converts
  cvt_bf16<<<(NB * NT * ND / 4 + 255) / 256, 256, 0, stream>>>(x, xb, NB * NT * ND / 4);
  cvt_bf16<<<(QKVD * ND / 4 + 255) / 256, 256, 0, stream>>>(w_qkv, wqkvb, QKVD * ND / 4);
  cvt_bf16<<<(ND * ND / 4 + 255) / 256, 256, 0, stream>>>(w_out, woutb, ND * ND / 4);

  // 2) qkv = x @ w_qkv^T   (M=4096, N=1536, K=1024)
  gemm_bf16_nt<<<dim3(NB * NT / 64, QKVD / 64), 256, 0, stream>>>(
      xb, wqkvb, qkv, NB * NT, QKVD, ND);

  // 3) rope + scales in place
  rope_scale<<<dim3(NT, 5, NB), 256, 0, stream>>>(qkv, cosT, sinT, q_scale, k_scale);

  // 4) attention -> bf16 ao
  attn<<<dim3(NT, NHEADS, NB), 256, 0, stream>>>(qkv, aob);

  // 5) out = ao @ w_out^T   (M=4096, N=1024, K=1024)
  gemm_bf16_nt<<<dim3(NB * NT / 64, ND / 64), 256, 0, stream>>>(
      aob, woutb, out, NB * NT, ND, ND);
}

// Round 2
// 292.624 us; speedup vs baseline: 11.0589x; 11.0589x over previous
//
#include <hip/hip_runtime.h>
#include <hip/hip_bf16.h>

#define NB 2
#define NT 2048
#define ND 1024
#define NHEADS 16
#define NKVH 4
#define HDIM 64
#define QKVD 1536   // (NHEADS + 2*NKVH) * HDIM

typedef __attribute__((ext_vector_type(8))) short short8;
typedef __attribute__((ext_vector_type(4))) float floatx4;

__device__ __forceinline__ unsigned short f2bf(float f) {
  union { float f; unsigned int u; } cv; cv.f = f;
  unsigned int u = cv.u;
  u += 0x7fffu + ((u >> 16) & 1u);   // round-to-nearest-even
  return (unsigned short)(u >> 16);
}
__device__ __forceinline__ float bf2f(unsigned short u) {
  union { unsigned int u; float f; } cv; cv.u = ((unsigned int)u) << 16; return cv.f;
}

// ---------------------------------------------------------------- converts
__global__ __launch_bounds__(256) void cvt_bf16(const float* __restrict__ in,
                                                unsigned short* __restrict__ out,
                                                int n4) {
  int i = blockIdx.x * 256 + threadIdx.x;
  if (i < n4) {
    float4 v = ((const float4*)in)[i];
    ushort4 o;
    o.x = f2bf(v.x); o.y = f2bf(v.y); o.z = f2bf(v.z); o.w = f2bf(v.w);
    ((ushort4*)out)[i] = o;
  }
}

// ------------------------------------------------- bf16 MFMA GEMM: C = A * B^T
__global__ __launch_bounds__(256) void gemm_bf16_nt(
    const unsigned short* __restrict__ A,
    const unsigned short* __restrict__ Bm,
    float* __restrict__ C, int M, int N, int K)
{
  __shared__ __align__(16) short As[64][40];
  __shared__ __align__(16) short Bs[64][40];

  const int tid  = threadIdx.x;
  const int wid  = tid >> 6;
  const int lane = tid & 63;
  const int quad = lane >> 4;
  const int l16  = lane & 15;
  const int m0 = blockIdx.x * 64;
  const int n0 = blockIdx.y * 64;

  const int srow   = tid >> 2;
  const int schunk = (tid & 3) * 8;

  const unsigned short* ag = A  + (size_t)(m0 + srow) * K + schunk;
  const unsigned short* bg = Bm + (size_t)(n0 + srow) * K + schunk;

  floatx4 acc[4] = {};

  for (int k0 = 0; k0 < K; k0 += 32) {
    short8 av = *(const short8*)(ag + k0);
    short8 bv = *(const short8*)(bg + k0);
    *(short8*)&As[srow][schunk] = av;
    *(short8*)&Bs[srow][schunk] = bv;
    __syncthreads();

    short8 af = *(const short8*)&As[wid * 16 + l16][quad * 8];
#pragma unroll
    for (int nt = 0; nt < 4; nt++) {
      short8 bf = *(const short8*)&Bs[nt * 16 + l16][quad * 8];
      acc[nt] = __builtin_amdgcn_mfma_f32_16x16x32_bf16(af, bf, acc[nt], 0, 0, 0);
    }
    __syncthreads();
  }

#pragma unroll
  for (int nt = 0; nt < 4; nt++) {
#pragma unroll
    for (int r = 0; r < 4; r++) {
      int m = m0 + wid * 16 + quad * 4 + r;
      int n = n0 + nt * 16 + l16;
      C[(size_t)m * N + n] = acc[nt][r];
    }
  }
}

// ------------------- RoPE(first 16 dims) + head scales, pack to bf16 head-major
// q gets an extra 1/sqrt(HD)=0.125 folded in (softmax scale).
// Grid: (NT, 5, NB), block 256 = 4 heads x 64 dims. Heads 0..15 -> qb, 16..19 -> kb.
__global__ __launch_bounds__(256) void rope_pack(
    const float* __restrict__ qkv,
    const float* __restrict__ cosT, const float* __restrict__ sinT,
    const float* __restrict__ q_scale, const float* __restrict__ k_scale,
    unsigned short* __restrict__ qb, unsigned short* __restrict__ kb)
{
  const int t  = blockIdx.x;
  const int b  = blockIdx.z;
  const int hh = blockIdx.y * 4 + (threadIdx.x >> 6);  // 0..19
  const int d  = threadIdx.x & 63;

  float scale; const float* src; unsigned short* dst;
  if (hh < NHEADS) {
    scale = q_scale[hh] * 0.125f;
    src = qkv + ((size_t)(b * NT + t)) * QKVD + hh * HDIM;
    dst = qb  + ((size_t)((b * NHEADS + hh) * NT + t)) * HDIM;
  } else {
    int kvh = hh - NHEADS;
    scale = k_scale[kvh];
    src = qkv + ((size_t)(b * NT + t)) * QKVD + NHEADS * HDIM + kvh * HDIM;
    dst = kb  + ((size_t)((b * NKVH + kvh) * NT + t)) * HDIM;
  }

  float out;
  if (d < 8) {
    float x1 = src[d], x2 = src[d + 8];
    float c = cosT[t * 8 + d], s = sinT[t * 8 + d];
    out = (x1 * c - x2 * s) * scale;
  } else if (d < 16) {
    float x1 = src[d - 8], x2 = src[d];
    float c = cosT[t * 8 + d - 8], s = sinT[t * 8 + d - 8];
    out = (x1 * s + x2 * c) * scale;
  } else {
    out = src[d] * scale;
  }
  dst[d] = f2bf(out);
}

// -------------------------------- transpose V to bf16 [B][NKV][HD][T] for fattn
// Grid: (NT/64, NKV, NB), block 256.
__global__ __launch_bounds__(256) void vT(const float* __restrict__ qkv,
                                          unsigned short* __restrict__ vtb)
{
  const int tt  = blockIdx.x;
  const int kvh = blockIdx.y;
  const int b   = blockIdx.z;
  const int tid = threadIdx.x;

  __shared__ float tile[64][65];

  // load 64 t-rows x 64 d fp32 (coalesced)
  {
    const int tl = tid >> 2, d0 = (tid & 3) * 16;
    const float* src = qkv + ((size_t)(b * NT + tt * 64 + tl)) * QKVD
                       + (NHEADS + NKVH) * HDIM + kvh * HDIM + d0;
#pragma unroll
    for (int j = 0; j < 16; j += 4) {
      float4 v = *(const float4*)(src + j);
      tile[tl][d0 + j + 0] = v.x; tile[tl][d0 + j + 1] = v.y;
      tile[tl][d0 + j + 2] = v.z; tile[tl][d0 + j + 3] = v.w;
    }
  }
  __syncthreads();
  // store transposed bf16 (coalesced along t)
  {
    const int dd = tid >> 2, t0 = (tid & 3) * 16;
    unsigned short* dst = vtb + ((size_t)((b * NKVH + kvh) * HDIM + dd)) * NT + tt * 64 + t0;
#pragma unroll
    for (int j = 0; j < 16; j++) dst[j] = f2bf(tile[t0 + j][dd]);
  }
}

// ----------------------------------------------------- flash attention (MFMA)
// Grid: (NT/64, NHEADS, NB), block 256 (4 waves; wave w owns q-rows w*16..w*16+15).
__global__ __launch_bounds__(256) void fattn(
    const unsigned short* __restrict__ qb,   // [B][NH][T][64], pre-scaled by 0.125*q_scale
    const unsigned short* __restrict__ kb,   // [B][NKV][T][64]
    const unsigned short* __restrict__ vtb,  // [B][NKV][64][T]
    unsigned short* __restrict__ aob)        // [B][T][NH*64]
{
  const int qt = (int)gridDim.x - 1 - (int)blockIdx.x;  // big tiles dispatch first
  const int h = blockIdx.y, b = blockIdx.z;
  const int kv = h >> 2;
  const int tid = threadIdx.x;
  const int wid = tid >> 6, lane = tid & 63;
  const int quad = lane >> 4, l16 = lane & 15;

  __shared__ __align__(16) short Qs[64][72];
  __shared__ __align__(16) short Ks[64][72];
  __shared__ __align__(16) short Vs[64][72];      // [d][t_local]
  __shared__ __align__(16) short Ps[4][16][72];   // per-wave P tile [q_row][t_local]

  // ---- stage Q tile (64 rows x 64 d)
  {
    const unsigned short* qg = qb + ((size_t)((b * NHEADS + h) * NT + qt * 64)) * HDIM;
#pragma unroll
    for (int i = 0; i < 2; i++) {
      int c = tid + i * 256;
      int r = c >> 3, cc = (c & 7) * 8;
      *(short8*)&Qs[r][cc] = *(const short8*)(qg + (size_t)r * HDIM + cc);
    }
  }
  __syncthreads();

  // Q A-fragments (constant over the whole K loop)
  short8 aq0 = *(const short8*)&Qs[wid * 16 + l16][quad * 8];
  short8 aq1 = *(const short8*)&Qs[wid * 16 + l16][32 + quad * 8];

  float m[4], l[4];
  floatx4 acc_o[4] = {};
#pragma unroll
  for (int r = 0; r < 4; r++) { m[r] = -INFINITY; l[r] = 0.f; }

  const unsigned short* kg0 = kb  + ((size_t)((b * NKVH + kv) * NT)) * HDIM;
  const unsigned short* vg0 = vtb + ((size_t)((b * NKVH + kv) * HDIM)) * NT;

  for (int jt = 0; jt <= qt; jt++) {
    // ---- stage K (row-major [t][d]) and V (transposed [d][t])
    const unsigned short* kg = kg0 + (size_t)jt * 64 * HDIM;
    const unsigned short* vg = vg0 + jt * 64;
#pragma unroll
    for (int i = 0; i < 2; i++) {
      int c = tid + i * 256;
      int r = c >> 3, cc = (c & 7) * 8;
      *(short8*)&Ks[r][cc] = *(const short8*)(kg + (size_t)r * HDIM + cc);
      *(short8*)&Vs[r][cc] = *(const short8*)(vg + (size_t)r * NT + cc);
    }
    __syncthreads();

    // ---- S = Q_tile(16) @ K_tile^T   (scale pre-folded into q)
    floatx4 s[4] = {};
#pragma unroll
    for (int nb = 0; nb < 4; nb++) {
      short8 bk0 = *(const short8*)&Ks[nb * 16 + l16][quad * 8];
      short8 bk1 = *(const short8*)&Ks[nb * 16 + l16][32 + quad * 8];
      s[nb] = __builtin_amdgcn_mfma_f32_16x16x32_bf16(aq0, bk0, s[nb], 0, 0, 0);
      s[nb] = __builtin_amdgcn_mfma_f32_16x16x32_bf16(aq1, bk1, s[nb], 0, 0, 0);
    }

    // ---- causal mask on the diagonal tile
    if (jt == qt) {
#pragma unroll
      for (int nb = 0; nb < 4; nb++) {
        int col = nb * 16 + l16;
#pragma unroll
        for (int r = 0; r < 4; r++) {
          int rowl = wid * 16 + quad * 4 + r;
          if (col > rowl) s[nb][r] = -INFINITY;
        }
      }
    }

    // ---- online softmax update (rows live in 16-lane quads)
    float p[4][4];
#pragma unroll
    for (int r = 0; r < 4; r++) {
      float rm = fmaxf(fmaxf(s[0][r], s[1][r]), fmaxf(s[2][r], s[3][r]));
#pragma unroll
      for (int off = 1; off < 16; off <<= 1) rm = fmaxf(rm, __shfl_xor(rm, off));
      float mn = fmaxf(m[r], rm);
      float alpha = __expf(m[r] - mn);
      float rs = 0.f;
#pragma unroll
      for (int nb = 0; nb < 4; nb++) { p[nb][r] = __expf(s[nb][r] - mn); rs += p[nb][r]; }
#pragma unroll
      for (int off = 1; off < 16; off <<= 1) rs += __shfl_xor(rs, off);
      l[r] = l[r] * alpha + rs;
      m[r] = mn;
#pragma unroll
      for (int nb = 0; nb < 4; nb++) acc_o[nb][r] *= alpha;
    }

    // ---- P -> LDS (C-layout to A-layout round trip)
#pragma unroll
    for (int nb = 0; nb < 4; nb++)
#pragma unroll
      for (int r = 0; r < 4; r++)
        Ps[wid][quad * 4 + r][nb * 16 + l16] = (short)f2bf(p[nb][r]);
    __syncthreads();

    // ---- O += P @ V
    short8 ap0 = *(const short8*)&Ps[wid][l16][quad * 8];
    short8 ap1 = *(const short8*)&Ps[wid][l16][32 + quad * 8];
#pragma unroll
    for (int nb = 0; nb < 4; nb++) {
      short8 bv0 = *(const short8*)&Vs[nb * 16 + l16][quad * 8];
      short8 bv1 = *(const short8*)&Vs[nb * 16 + l16][32 + quad * 8];
      acc_o[nb] = __builtin_amdgcn_mfma_f32_16x16x32_bf16(ap0, bv0, acc_o[nb], 0, 0, 0);
      acc_o[nb] = __builtin_amdgcn_mfma_f32_16x16x32_bf16(ap1, bv1, acc_o[nb], 0, 0, 0);
    }
    __syncthreads();   // protect Ks/Vs/Ps before next staging
  }

  // ---- epilogue: normalize, v-orthogonalize (v for diagonal tile still in Vs), store
#pragma unroll
  for (int r = 0; r < 4; r++) {
    const int rowl = wid * 16 + quad * 4 + r;
    float invl = 1.f / l[r];
    float vd[4];
    float dot = 0.f, vv = 0.f;
#pragma unroll
    for (int nb = 0; nb < 4; nb++) {
      vd[nb] = bf2f((unsigned short)Vs[nb * 16 + l16][rowl]);
      dot += acc_o[nb][r] * invl * vd[nb];
      vv  += vd[nb] * vd[nb];
    }
#pragma unroll
    for (int off = 1; off < 16; off <<= 1) {
      dot += __shfl_xor(dot, off);
      vv  += __shfl_xor(vv, off);
    }
    float coef = dot / fmaxf(vv, 1e-8f);
    unsigned short* dst = aob + ((size_t)(b * NT + qt * 64 + rowl)) * ND + h * HDIM + l16;
#pragma unroll
    for (int nb = 0; nb < 4; nb++) {
      float oo = acc_o[nb][r] * invl - coef * vd[nb];
      dst[nb * 16] = f2bf(oo);
    }
  }
}

// ---------------------------------------------------------------------- launch
extern "C" void kernel_launch(void* const* d_in, const int* in_sizes, int n_in,
                              void* d_out, int out_size, void* d_ws, size_t ws_size,
                              hipStream_t stream) {
  const float* x       = (const float*)d_in[0];
  const float* cosT    = (const float*)d_in[1];
  const float* sinT    = (const float*)d_in[2];
  const float* w_qkv   = (const float*)d_in[4];
  const float* w_out   = (const float*)d_in[5];
  const float* q_scale = (const float*)d_in[6];
  const float* k_scale = (const float*)d_in[7];
  float* out = (float*)d_out;

  // workspace layout (overlays: qb reuses xb, kb reuses wqkvb — dead after GEMM1)
  char* ws = (char*)d_ws;
  unsigned short* xb    = (unsigned short*)ws;                              // 8 MB
  unsigned short* qb    = xb;                                               // overlay
  unsigned short* wqkvb = (unsigned short*)(ws + 8388608);                  // 3 MB
  unsigned short* kb    = wqkvb;                                            // overlay (2 MB)
  unsigned short* woutb = (unsigned short*)(ws + 8388608 + 3145728);        // 2 MB
  float*          qkv   = (float*)(ws + 8388608 + 3145728 + 2097152);       // 25.2 MB
  unsigned short* vtb   = (unsigned short*)(ws + 8388608 + 3145728 + 2097152 + 25165824); // 2 MB
  unsigned short* aob   = (unsigned short*)(ws + 8388608 + 3145728 + 2097152 + 25165824 + 2097152); // 8 MB

  // 1) fp32 -> bf16 converts
  cvt_bf16<<<(NB * NT * ND / 4 + 255) / 256, 256, 0, stream>>>(x, xb, NB * NT * ND / 4);
  cvt_bf16<<<(QKVD * ND / 4 + 255) / 256, 256, 0, stream>>>(w_qkv, wqkvb, QKVD * ND / 4);
  cvt_bf16<<<(ND * ND / 4 + 255) / 256, 256, 0, stream>>>(w_out, woutb, ND * ND / 4);

  // 2) qkv = x @ w_qkv^T   (M=4096, N=1536, K=1024)
  gemm_bf16_nt<<<dim3(NB * NT / 64, QKVD / 64), 256, 0, stream>>>(
      xb, wqkvb, qkv, NB * NT, QKVD, ND);

  // 3) rope + scales -> bf16 q/k head-major; transpose v -> bf16 [d][t]
  rope_pack<<<dim3(NT, 5, NB), 256, 0, stream>>>(qkv, cosT, sinT, q_scale, k_scale, qb, kb);
  vT<<<dim3(NT / 64, NKVH, NB), 256, 0, stream>>>(qkv, vtb);

  // 4) flash attention -> bf16 ao
  fattn<<<dim3(NT / 64, NHEADS, NB), 256, 0, stream>>>(qb, kb, vtb, aob);

  // 5) out = ao @ w_out^T   (M=4096, N=1024, K=1024)
  gemm_bf16_nt<<<dim3(NB * NT / 64, ND / 64), 256, 0, stream>>>(
      aob, woutb, out, NB * NT, ND, ND);
}

// Round 3
// 253.193 us; speedup vs baseline: 12.7811x; 1.1557x over previous
//
#include <hip/hip_runtime.h>
#include <hip/hip_bf16.h>

#define NB 2
#define NT 2048
#define ND 1024
#define NHEADS 16
#define NKVH 4
#define HDIM 64
#define QKVD 1536   // (NHEADS + 2*NKVH) * HDIM

typedef __attribute__((ext_vector_type(8))) short short8;
typedef __attribute__((ext_vector_type(4))) float floatx4;

__device__ __forceinline__ unsigned short f2bf(float f) {
  union { float f; unsigned int u; } cv; cv.f = f;
  unsigned int u = cv.u;
  u += 0x7fffu + ((u >> 16) & 1u);   // round-to-nearest-even
  return (unsigned short)(u >> 16);
}
__device__ __forceinline__ float bf2f(unsigned short u) {
  union { unsigned int u; float f; } cv; cv.u = ((unsigned int)u) << 16; return cv.f;
}

// ---------------------------------------------------------------- converts
__global__ __launch_bounds__(256) void cvt_bf16(const float* __restrict__ in,
                                                unsigned short* __restrict__ out,
                                                int n4) {
  int i = blockIdx.x * 256 + threadIdx.x;
  if (i < n4) {
    float4 v = ((const float4*)in)[i];
    ushort4 o;
    o.x = f2bf(v.x); o.y = f2bf(v.y); o.z = f2bf(v.z); o.w = f2bf(v.w);
    ((ushort4*)out)[i] = o;
  }
}

// ---------------------- bf16 MFMA GEMM: C = A * B^T, 128x128 tile, 4 waves
// Each wave owns a 64x64 quadrant (4x4 grid of 16x16x32 MFMAs).
__global__ __launch_bounds__(256) void gemm128(
    const unsigned short* __restrict__ A,
    const unsigned short* __restrict__ Bm,
    float* __restrict__ C, int M, int N, int K)
{
  __shared__ __align__(16) short As[128][40];
  __shared__ __align__(16) short Bs[128][40];

  const int tid  = threadIdx.x;
  const int wid  = tid >> 6;
  const int lane = tid & 63;
  const int quad = lane >> 4;
  const int l16  = lane & 15;
  const int wm = (wid >> 1) * 64;
  const int wn = (wid & 1) * 64;
  const int m0 = blockIdx.x * 128;
  const int n0 = blockIdx.y * 128;

  // staging: 128 rows x 32 k-shorts per tile; each thread 2 chunks of A and B
  const int r0 = tid >> 2,          c0 = (tid & 3) * 8;
  const int r1 = (tid + 256) >> 2,  c1 = ((tid + 256) & 3) * 8;

  const unsigned short* ag0 = A  + (size_t)(m0 + r0) * K + c0;
  const unsigned short* ag1 = A  + (size_t)(m0 + r1) * K + c1;
  const unsigned short* bg0 = Bm + (size_t)(n0 + r0) * K + c0;
  const unsigned short* bg1 = Bm + (size_t)(n0 + r1) * K + c1;

  floatx4 acc[4][4] = {};

  for (int k0 = 0; k0 < K; k0 += 32) {
    short8 a0 = *(const short8*)(ag0 + k0);
    short8 a1 = *(const short8*)(ag1 + k0);
    short8 b0 = *(const short8*)(bg0 + k0);
    short8 b1 = *(const short8*)(bg1 + k0);
    *(short8*)&As[r0][c0] = a0;
    *(short8*)&As[r1][c1] = a1;
    *(short8*)&Bs[r0][c0] = b0;
    *(short8*)&Bs[r1][c1] = b1;
    __syncthreads();

    short8 af[4], bf[4];
#pragma unroll
    for (int mi = 0; mi < 4; mi++) af[mi] = *(const short8*)&As[wm + mi * 16 + l16][quad * 8];
#pragma unroll
    for (int ni = 0; ni < 4; ni++) bf[ni] = *(const short8*)&Bs[wn + ni * 16 + l16][quad * 8];
#pragma unroll
    for (int mi = 0; mi < 4; mi++)
#pragma unroll
      for (int ni = 0; ni < 4; ni++)
        acc[mi][ni] = __builtin_amdgcn_mfma_f32_16x16x32_bf16(af[mi], bf[ni], acc[mi][ni], 0, 0, 0);
    __syncthreads();
  }

#pragma unroll
  for (int mi = 0; mi < 4; mi++)
#pragma unroll
    for (int ni = 0; ni < 4; ni++)
#pragma unroll
      for (int r = 0; r < 4; r++) {
        int m = m0 + wm + mi * 16 + quad * 4 + r;
        int n = n0 + wn + ni * 16 + l16;
        C[(size_t)m * N + n] = acc[mi][ni][r];
      }
}

// ------------------- RoPE(first 16 dims) + head scales, pack to bf16 head-major
// q gets 0.125*log2(e)*q_scale folded in (softmax in base 2, no max tracking).
__global__ __launch_bounds__(256) void rope_pack(
    const float* __restrict__ qkv,
    const float* __restrict__ cosT, const float* __restrict__ sinT,
    const float* __restrict__ q_scale, const float* __restrict__ k_scale,
    unsigned short* __restrict__ qb, unsigned short* __restrict__ kb)
{
  const int t  = blockIdx.x;
  const int b  = blockIdx.z;
  const int hh = blockIdx.y * 4 + (threadIdx.x >> 6);  // 0..19
  const int d  = threadIdx.x & 63;

  float scale; const float* src; unsigned short* dst;
  if (hh < NHEADS) {
    scale = q_scale[hh] * (0.125f * 1.44269504088896f);
    src = qkv + ((size_t)(b * NT + t)) * QKVD + hh * HDIM;
    dst = qb  + ((size_t)((b * NHEADS + hh) * NT + t)) * HDIM;
  } else {
    int kvh = hh - NHEADS;
    scale = k_scale[kvh];
    src = qkv + ((size_t)(b * NT + t)) * QKVD + NHEADS * HDIM + kvh * HDIM;
    dst = kb  + ((size_t)((b * NKVH + kvh) * NT + t)) * HDIM;
  }

  float out;
  if (d < 8) {
    float x1 = src[d], x2 = src[d + 8];
    float c = cosT[t * 8 + d], s = sinT[t * 8 + d];
    out = (x1 * c - x2 * s) * scale;
  } else if (d < 16) {
    float x1 = src[d - 8], x2 = src[d];
    float c = cosT[t * 8 + d - 8], s = sinT[t * 8 + d - 8];
    out = (x1 * s + x2 * c) * scale;
  } else {
    out = src[d] * scale;
  }
  dst[d] = f2bf(out);
}

// -------------------------------- transpose V to bf16 [B][NKV][HD][T] for fattn
__global__ __launch_bounds__(256) void vT(const float* __restrict__ qkv,
                                          unsigned short* __restrict__ vtb)
{
  const int tt  = blockIdx.x;
  const int kvh = blockIdx.y;
  const int b   = blockIdx.z;
  const int tid = threadIdx.x;

  __shared__ float tile[64][65];

  {
    const int tl = tid >> 2, d0 = (tid & 3) * 16;
    const float* src = qkv + ((size_t)(b * NT + tt * 64 + tl)) * QKVD
                       + (NHEADS + NKVH) * HDIM + kvh * HDIM + d0;
#pragma unroll
    for (int j = 0; j < 16; j += 4) {
      float4 v = *(const float4*)(src + j);
      tile[tl][d0 + j + 0] = v.x; tile[tl][d0 + j + 1] = v.y;
      tile[tl][d0 + j + 2] = v.z; tile[tl][d0 + j + 3] = v.w;
    }
  }
  __syncthreads();
  {
    const int dd = tid >> 2, t0 = (tid & 3) * 16;
    unsigned short* dst = vtb + ((size_t)((b * NKVH + kvh) * HDIM + dd)) * NT + tt * 64 + t0;
#pragma unroll
    for (int j = 0; j < 16; j++) dst[j] = f2bf(tile[t0 + j][dd]);
  }
}

// ----------------------------------------------------- flash attention (MFMA)
// No max tracking (scores bounded; base-2 softmax pre-scaled into q).
// XOR-swizzled LDS (stride 64, chunk ^ (row&7)) -> ~conflict-free.
// Grid: (NT/64, NHEADS, NB), block 256.
__global__ __launch_bounds__(256) void fattn(
    const unsigned short* __restrict__ qb,   // [B][NH][T][64]
    const unsigned short* __restrict__ kb,   // [B][NKV][T][64]
    const unsigned short* __restrict__ vtb,  // [B][NKV][64][T]
    unsigned short* __restrict__ aob)        // [B][T][NH*64]
{
  const int qt = (int)gridDim.x - 1 - (int)blockIdx.x;  // long blocks first
  const int h = blockIdx.y, b = blockIdx.z;
  const int kv = h >> 2;
  const int tid = threadIdx.x;
  const int wid = tid >> 6, lane = tid & 63;
  const int quad = lane >> 4, l16 = lane & 15;
  const int hi8 = l16 >> 3, lo8 = l16 & 7;

  __shared__ __align__(16) short Ks[64][64];     // [t][d], chunk^(t&7)
  __shared__ __align__(16) short Vs[64][64];     // [d][t], chunk^(d&7)
  __shared__ __align__(16) short Ps[4][16][64];  // [wave][q][t], chunk^(q&7)

  // ---- Q fragments straight from global
  const unsigned short* qg = qb + ((size_t)((b * NHEADS + h) * NT + qt * 64)) * HDIM;
  const int qrow = wid * 16 + l16;
  short8 aq0 = *(const short8*)(qg + (size_t)qrow * HDIM + quad * 8);
  short8 aq1 = *(const short8*)(qg + (size_t)qrow * HDIM + 32 + quad * 8);

  // ---- staging addresses (swizzled LDS, fixed per thread)
  const int sr0 = tid >> 3,          sc0 = tid & 7;
  const int sr1 = (tid + 256) >> 3,  sc1 = (tid + 256) & 7;
  short* kst0 = &Ks[sr0][(sc0 ^ (sr0 & 7)) * 8];
  short* kst1 = &Ks[sr1][(sc1 ^ (sr1 & 7)) * 8];
  short* vst0 = &Vs[sr0][(sc0 ^ (sr0 & 7)) * 8];
  short* vst1 = &Vs[sr1][(sc1 ^ (sr1 & 7)) * 8];
  const unsigned short* kgp0 = kb + ((size_t)((b * NKVH + kv) * NT) + sr0) * HDIM + sc0 * 8;
  const unsigned short* kgp1 = kb + ((size_t)((b * NKVH + kv) * NT) + sr1) * HDIM + sc1 * 8;
  const unsigned short* vgp0 = vtb + ((size_t)((b * NKVH + kv) * HDIM) + sr0) * NT + sc0 * 8;
  const unsigned short* vgp1 = vtb + ((size_t)((b * NKVH + kv) * HDIM) + sr1) * NT + sc1 * 8;

  // ---- fragment-read swizzled column offsets (row&7 == l16&7 for all reads)
  const int cs0 = (quad ^ lo8) * 8;   // k-chunk 0..31
  const int cs1 = cs0 ^ 32;           // k-chunk 32..63

  // ---- P write offsets (short index into Ps), loop-invariant
  int pwo[4][4];
#pragma unroll
  for (int r = 0; r < 4; r++) {
    const int row = quad * 4 + r;
#pragma unroll
    for (int nb = 0; nb < 4; nb++)
      pwo[r][nb] = wid * 1024 + row * 64 + (((nb * 2 + hi8) ^ (row & 7)) * 8) + lo8;
  }
  short* psf = &Ps[0][0][0];

  floatx4 acc_o[4] = {};
  float lsum[4] = {0.f, 0.f, 0.f, 0.f};

  for (int jt = 0; jt <= qt; jt++) {
    // ---- stage K[t][d] and V[d][t] (swizzled)
    *(short8*)kst0 = *(const short8*)(kgp0 + (size_t)jt * 64 * HDIM);
    *(short8*)kst1 = *(const short8*)(kgp1 + (size_t)jt * 64 * HDIM);
    *(short8*)vst0 = *(const short8*)(vgp0 + jt * 64);
    *(short8*)vst1 = *(const short8*)(vgp1 + jt * 64);
    __syncthreads();

    // ---- S = Q @ K^T (rows quad*4+r of wave's 16, cols nb*16+l16)
    floatx4 s[4] = {};
#pragma unroll
    for (int nb = 0; nb < 4; nb++) {
      short8 bk0 = *(const short8*)&Ks[nb * 16 + l16][cs0];
      short8 bk1 = *(const short8*)&Ks[nb * 16 + l16][cs1];
      s[nb] = __builtin_amdgcn_mfma_f32_16x16x32_bf16(aq0, bk0, s[nb], 0, 0, 0);
      s[nb] = __builtin_amdgcn_mfma_f32_16x16x32_bf16(aq1, bk1, s[nb], 0, 0, 0);
    }

    if (jt == qt) {   // causal mask, diagonal tile only
#pragma unroll
      for (int nb = 0; nb < 4; nb++) {
        int col = nb * 16 + l16;
#pragma unroll
        for (int r = 0; r < 4; r++)
          if (col > wid * 16 + quad * 4 + r) s[nb][r] = -INFINITY;
      }
    }

    // ---- p = exp2(s); per-lane l partials; write P (no cross-lane ops!)
#pragma unroll
    for (int r = 0; r < 4; r++) {
#pragma unroll
      for (int nb = 0; nb < 4; nb++) {
        float p = __builtin_amdgcn_exp2f(s[nb][r]);
        lsum[r] += p;
        psf[pwo[r][nb]] = (short)f2bf(p);
      }
    }
    __syncthreads();

    // ---- O += P @ V
    short8 ap0 = *(const short8*)&Ps[wid][l16][cs0];
    short8 ap1 = *(const short8*)&Ps[wid][l16][cs1];
#pragma unroll
    for (int nb = 0; nb < 4; nb++) {
      short8 bv0 = *(const short8*)&Vs[nb * 16 + l16][cs0];
      short8 bv1 = *(const short8*)&Vs[nb * 16 + l16][cs1];
      acc_o[nb] = __builtin_amdgcn_mfma_f32_16x16x32_bf16(ap0, bv0, acc_o[nb], 0, 0, 0);
      acc_o[nb] = __builtin_amdgcn_mfma_f32_16x16x32_bf16(ap1, bv1, acc_o[nb], 0, 0, 0);
    }
    __syncthreads();   // protect Ks/Vs/Ps before next staging
  }

  // ---- epilogue: reduce l, normalize, v-orthogonalize (diag V still in Vs)
#pragma unroll
  for (int r = 0; r < 4; r++) {
    float ls = lsum[r];
#pragma unroll
    for (int off = 1; off < 16; off <<= 1) ls += __shfl_xor(ls, off);
    const float invl = 1.f / ls;

    const int rowl = wid * 16 + quad * 4 + r;
    const int vcol = ((rowl >> 3) ^ lo8) * 8 + (rowl & 7);   // swizzled t index
    float vd[4], dot = 0.f, vv = 0.f;
#pragma unroll
    for (int nb = 0; nb < 4; nb++) {
      vd[nb] = bf2f((unsigned short)Vs[nb * 16 + l16][vcol]);
      dot += acc_o[nb][r] * invl * vd[nb];
      vv  += vd[nb] * vd[nb];
    }
#pragma unroll
    for (int off = 1; off < 16; off <<= 1) {
      dot += __shfl_xor(dot, off);
      vv  += __shfl_xor(vv, off);
    }
    const float coef = dot / fmaxf(vv, 1e-8f);
    unsigned short* dst = aob + ((size_t)(b * NT + qt * 64 + rowl)) * ND + h * HDIM + l16;
#pragma unroll
    for (int nb = 0; nb < 4; nb++)
      dst[nb * 16] = f2bf(acc_o[nb][r] * invl - coef * vd[nb]);
  }
}

// ---------------------------------------------------------------------- launch
extern "C" void kernel_launch(void* const* d_in, const int* in_sizes, int n_in,
                              void* d_out, int out_size, void* d_ws, size_t ws_size,
                              hipStream_t stream) {
  const float* x       = (const float*)d_in[0];
  const float* cosT    = (const float*)d_in[1];
  const float* sinT    = (const float*)d_in[2];
  const float* w_qkv   = (const float*)d_in[4];
  const float* w_out   = (const float*)d_in[5];
  const float* q_scale = (const float*)d_in[6];
  const float* k_scale = (const float*)d_in[7];
  float* out = (float*)d_out;

  char* ws = (char*)d_ws;
  unsigned short* xb    = (unsigned short*)ws;                              // 8 MB
  unsigned short* qb    = xb;                                               // overlay
  unsigned short* wqkvb = (unsigned short*)(ws + 8388608);                  // 3 MB
  unsigned short* kb    = wqkvb;                                            // overlay (2 MB)
  unsigned short* woutb = (unsigned short*)(ws + 8388608 + 3145728);        // 2 MB
  float*          qkv   = (float*)(ws + 8388608 + 3145728 + 2097152);       // 25.2 MB
  unsigned short* vtb   = (unsigned short*)(ws + 8388608 + 3145728 + 2097152 + 25165824); // 2 MB
  unsigned short* aob   = (unsigned short*)(ws + 8388608 + 3145728 + 2097152 + 25165824 + 2097152); // 8 MB

  cvt_bf16<<<(NB * NT * ND / 4 + 255) / 256, 256, 0, stream>>>(x, xb, NB * NT * ND / 4);
  cvt_bf16<<<(QKVD * ND / 4 + 255) / 256, 256, 0, stream>>>(w_qkv, wqkvb, QKVD * ND / 4);
  cvt_bf16<<<(ND * ND / 4 + 255) / 256, 256, 0, stream>>>(w_out, woutb, ND * ND / 4);

  // qkv = x @ w_qkv^T   (M=4096, N=1536, K=1024)
  gemm128<<<dim3(NB * NT / 128, QKVD / 128), 256, 0, stream>>>(
      xb, wqkvb, qkv, NB * NT, QKVD, ND);

  rope_pack<<<dim3(NT, 5, NB), 256, 0, stream>>>(qkv, cosT, sinT, q_scale, k_scale, qb, kb);
  vT<<<dim3(NT / 64, NKVH, NB), 256, 0, stream>>>(qkv, vtb);

  fattn<<<dim3(NT / 64, NHEADS, NB), 256, 0, stream>>>(qb, kb, vtb, aob);

  // out = ao @ w_out^T   (M=4096, N=1024, K=1024)
  gemm128<<<dim3(NB * NT / 128, ND / 128), 256, 0, stream>>>(
      aob, woutb, out, NB * NT, ND, ND);
}

// Round 4
// 220.145 us; speedup vs baseline: 14.6998x; 1.1501x over previous
//
#include <hip/hip_runtime.h>
#include <hip/hip_bf16.h>

#define NB 2
#define NT 2048
#define ND 1024
#define NHEADS 16
#define NKVH 4
#define HDIM 64
#define QKVD 1536   // (NHEADS + 2*NKVH) * HDIM

typedef __attribute__((ext_vector_type(8))) short short8;
typedef __attribute__((ext_vector_type(4))) float floatx4;

__device__ __forceinline__ unsigned short f2bf(float f) {
  union { float f; unsigned int u; } cv; cv.f = f;
  unsigned int u = cv.u;
  u += 0x7fffu + ((u >> 16) & 1u);   // round-to-nearest-even
  return (unsigned short)(u >> 16);
}
__device__ __forceinline__ float bf2f(unsigned short u) {
  union { unsigned int u; float f; } cv; cv.u = ((unsigned int)u) << 16; return cv.f;
}

// ---------------------------------------------------------------- converts
__global__ __launch_bounds__(256) void cvt_bf16(const float* __restrict__ in,
                                                unsigned short* __restrict__ out,
                                                int n4) {
  int i = blockIdx.x * 256 + threadIdx.x;
  if (i < n4) {
    float4 v = ((const float4*)in)[i];
    ushort4 o;
    o.x = f2bf(v.x); o.y = f2bf(v.y); o.z = f2bf(v.z); o.w = f2bf(v.w);
    ((ushort4*)out)[i] = o;
  }
}

// ---------------- bf16 MFMA GEMM: C = A * B^T, 128x64 tile (high block count)
// 4 waves; wave w owns rows w*32..w*32+31 x all 64 cols (2x4 frags).
__global__ __launch_bounds__(256) void gemm12864(
    const unsigned short* __restrict__ A,
    const unsigned short* __restrict__ Bm,
    float* __restrict__ C, int M, int N, int K)
{
  __shared__ __align__(16) short As[128][40];
  __shared__ __align__(16) short Bs[64][40];

  const int tid  = threadIdx.x;
  const int wid  = tid >> 6;
  const int lane = tid & 63;
  const int quad = lane >> 4;
  const int l16  = lane & 15;
  const int wm = wid * 32;
  const int m0 = blockIdx.x * 128;
  const int n0 = blockIdx.y * 64;

  const int r0 = tid >> 2, c0 = (tid & 3) * 8;
  const unsigned short* ag0 = A  + (size_t)(m0 + r0) * K + c0;
  const unsigned short* ag1 = ag0 + (size_t)64 * K;
  const unsigned short* bg0 = Bm + (size_t)(n0 + r0) * K + c0;

  floatx4 acc[2][4] = {};

  for (int k0 = 0; k0 < K; k0 += 32) {
    short8 a0 = *(const short8*)(ag0 + k0);
    short8 a1 = *(const short8*)(ag1 + k0);
    short8 b0 = *(const short8*)(bg0 + k0);
    *(short8*)&As[r0][c0]      = a0;
    *(short8*)&As[r0 + 64][c0] = a1;
    *(short8*)&Bs[r0][c0]      = b0;
    __syncthreads();

    short8 af[2], bf[4];
#pragma unroll
    for (int mi = 0; mi < 2; mi++) af[mi] = *(const short8*)&As[wm + mi * 16 + l16][quad * 8];
#pragma unroll
    for (int ni = 0; ni < 4; ni++) bf[ni] = *(const short8*)&Bs[ni * 16 + l16][quad * 8];
#pragma unroll
    for (int mi = 0; mi < 2; mi++)
#pragma unroll
      for (int ni = 0; ni < 4; ni++)
        acc[mi][ni] = __builtin_amdgcn_mfma_f32_16x16x32_bf16(af[mi], bf[ni], acc[mi][ni], 0, 0, 0);
    __syncthreads();
  }

#pragma unroll
  for (int mi = 0; mi < 2; mi++)
#pragma unroll
    for (int ni = 0; ni < 4; ni++)
#pragma unroll
      for (int r = 0; r < 4; r++) {
        int m = m0 + wm + mi * 16 + quad * 4 + r;
        int n = n0 + ni * 16 + l16;
        C[(size_t)m * N + n] = acc[mi][ni][r];
      }
}

// ------------------- RoPE(first 16 dims) + head scales, pack to bf16 head-major
// q gets 0.125*log2(e)*q_scale folded in. Each block handles 8 t values.
__global__ __launch_bounds__(256) void rope_pack(
    const float* __restrict__ qkv,
    const float* __restrict__ cosT, const float* __restrict__ sinT,
    const float* __restrict__ q_scale, const float* __restrict__ k_scale,
    unsigned short* __restrict__ qb, unsigned short* __restrict__ kb)
{
  const int b  = blockIdx.z;
  const int hh = blockIdx.y * 4 + (threadIdx.x >> 6);  // 0..19
  const int d  = threadIdx.x & 63;

  float scale; int soff; unsigned short* dbase;
  if (hh < NHEADS) {
    scale = q_scale[hh] * (0.125f * 1.44269504088896f);
    soff = hh * HDIM;
    dbase = qb + ((size_t)(b * NHEADS + hh) * NT) * HDIM;
  } else {
    int kvh = hh - NHEADS;
    scale = k_scale[kvh];
    soff = NHEADS * HDIM + kvh * HDIM;
    dbase = kb + ((size_t)(b * NKVH + kvh) * NT) * HDIM;
  }

  for (int i = 0; i < 8; i++) {
    const int t = blockIdx.x * 8 + i;
    const float* src = qkv + ((size_t)(b * NT + t)) * QKVD + soff;
    float out;
    if (d < 8) {
      float x1 = src[d], x2 = src[d + 8];
      float c = cosT[t * 8 + d], s = sinT[t * 8 + d];
      out = (x1 * c - x2 * s) * scale;
    } else if (d < 16) {
      float x1 = src[d - 8], x2 = src[d];
      float c = cosT[t * 8 + d - 8], s = sinT[t * 8 + d - 8];
      out = (x1 * s + x2 * c) * scale;
    } else {
      out = src[d] * scale;
    }
    dbase[(size_t)t * HDIM + d] = f2bf(out);
  }
}

// -------------------------------- transpose V to bf16 [B][NKV][HD][T] for fattn
__global__ __launch_bounds__(256) void vT(const float* __restrict__ qkv,
                                          unsigned short* __restrict__ vtb)
{
  const int tt  = blockIdx.x;
  const int kvh = blockIdx.y;
  const int b   = blockIdx.z;
  const int tid = threadIdx.x;

  __shared__ float tile[64][65];

  {
    const int tl = tid >> 2, d0 = (tid & 3) * 16;
    const float* src = qkv + ((size_t)(b * NT + tt * 64 + tl)) * QKVD
                       + (NHEADS + NKVH) * HDIM + kvh * HDIM + d0;
#pragma unroll
    for (int j = 0; j < 16; j += 4) {
      float4 v = *(const float4*)(src + j);
      tile[tl][d0 + j + 0] = v.x; tile[tl][d0 + j + 1] = v.y;
      tile[tl][d0 + j + 2] = v.z; tile[tl][d0 + j + 3] = v.w;
    }
  }
  __syncthreads();
  {
    const int dd = tid >> 2, t0 = (tid & 3) * 16;
    unsigned short* dst = vtb + ((size_t)((b * NKVH + kvh) * HDIM + dd)) * NT + tt * 64 + t0;
#pragma unroll
    for (int j = 0; j < 16; j++) dst[j] = f2bf(tile[t0 + j][dd]);
  }
}

// ----------------------------------------------------- flash attention (MFMA)
// Fixed-m base-2 softmax (additive partials). Uniform KV-chunking:
//   idx 0..15  : qt=16+idx, chunk0 (jt 0..15)  -> partial slot
//   idx 16..47 : rel=idx-16, s=16-rel/2;
//                rel even -> qt=s-1 full (direct epilogue)
//                rel odd  -> qt=s+15 chunk1 (jt 16..qt) -> partial slot
// Register prefetch of next K/V tile overlaps loads with compute.
__global__ __launch_bounds__(256) void fattn(
    const unsigned short* __restrict__ qb,   // [B][NH][T][64]
    const unsigned short* __restrict__ kb,   // [B][NKV][T][64]
    const unsigned short* __restrict__ vtb,  // [B][NKV][64][T]
    unsigned short* __restrict__ aob,        // [B][T][NH*64]
    float* __restrict__ pbuf)                // 1024 slots x (64*64 O + 64 l) fp32
{
  const int idx = blockIdx.x;
  const int h = blockIdx.y, b = blockIdx.z;
  const int kv = h >> 2;

  int qt, j0, cnt, chunk; bool direct;
  if (idx < 16) { qt = 16 + idx; j0 = 0; cnt = 16; chunk = 0; direct = false; }
  else {
    int rel = idx - 16, s = 16 - (rel >> 1);
    if ((rel & 1) == 0) { qt = s - 1;  j0 = 0;  cnt = s; chunk = 0; direct = true;  }
    else                { qt = s + 15; j0 = 16; cnt = s; chunk = 1; direct = false; }
  }

  const int tid = threadIdx.x;
  const int wid = tid >> 6, lane = tid & 63;
  const int quad = lane >> 4, l16 = lane & 15;
  const int hi8 = l16 >> 3, lo8 = l16 & 7;

  __shared__ __align__(16) short Ks[64][64];     // [t][d], chunk^(t&7)
  __shared__ __align__(16) short Vs[64][64];     // [d][t], chunk^(d&7)
  __shared__ __align__(16) short Ps[4][16][64];  // [wave][q][t], chunk^(q&7)

  // ---- Q fragments straight from global
  const unsigned short* qg = qb + ((size_t)((b * NHEADS + h) * NT + qt * 64)) * HDIM;
  const int qrow = wid * 16 + l16;
  short8 aq0 = *(const short8*)(qg + (size_t)qrow * HDIM + quad * 8);
  short8 aq1 = *(const short8*)(qg + (size_t)qrow * HDIM + 32 + quad * 8);

  // ---- staging addresses (swizzled LDS, fixed per thread)
  const int sr0 = tid >> 3,          sc0 = tid & 7;
  const int sr1 = (tid + 256) >> 3,  sc1 = (tid + 256) & 7;
  short* kst0 = &Ks[sr0][(sc0 ^ (sr0 & 7)) * 8];
  short* kst1 = &Ks[sr1][(sc1 ^ (sr1 & 7)) * 8];
  short* vst0 = &Vs[sr0][(sc0 ^ (sr0 & 7)) * 8];
  short* vst1 = &Vs[sr1][(sc1 ^ (sr1 & 7)) * 8];
  const unsigned short* kgp0 = kb + ((size_t)((b * NKVH + kv) * NT) + sr0) * HDIM + sc0 * 8;
  const unsigned short* kgp1 = kb + ((size_t)((b * NKVH + kv) * NT) + sr1) * HDIM + sc1 * 8;
  const unsigned short* vgp0 = vtb + ((size_t)((b * NKVH + kv) * HDIM) + sr0) * NT + sc0 * 8;
  const unsigned short* vgp1 = vtb + ((size_t)((b * NKVH + kv) * HDIM) + sr1) * NT + sc1 * 8;

  // ---- fragment-read swizzled column offsets
  const int cs0 = (quad ^ lo8) * 8;
  const int cs1 = cs0 ^ 32;

  // ---- P write offsets, loop-invariant
  int pwo[4][4];
#pragma unroll
  for (int r = 0; r < 4; r++) {
    const int row = quad * 4 + r;
#pragma unroll
    for (int nb = 0; nb < 4; nb++)
      pwo[r][nb] = wid * 1024 + row * 64 + (((nb * 2 + hi8) ^ (row & 7)) * 8) + lo8;
  }
  short* psf = &Ps[0][0][0];

  floatx4 acc_o[4] = {};
  float lsum[4] = {0.f, 0.f, 0.f, 0.f};

  // ---- prefetch first tile
  short8 pk0 = *(const short8*)(kgp0 + (size_t)j0 * 64 * HDIM);
  short8 pk1 = *(const short8*)(kgp1 + (size_t)j0 * 64 * HDIM);
  short8 pv0 = *(const short8*)(vgp0 + j0 * 64);
  short8 pv1 = *(const short8*)(vgp1 + j0 * 64);

  for (int i = 0; i < cnt; i++) {
    const int jt = j0 + i;
    *(short8*)kst0 = pk0;
    *(short8*)kst1 = pk1;
    *(short8*)vst0 = pv0;
    *(short8*)vst1 = pv1;
    __syncthreads();

    if (i + 1 < cnt) {   // prefetch next tile (overlaps with compute below)
      pk0 = *(const short8*)(kgp0 + (size_t)(jt + 1) * 64 * HDIM);
      pk1 = *(const short8*)(kgp1 + (size_t)(jt + 1) * 64 * HDIM);
      pv0 = *(const short8*)(vgp0 + (jt + 1) * 64);
      pv1 = *(const short8*)(vgp1 + (jt + 1) * 64);
    }

    // ---- S = Q @ K^T
    floatx4 s[4] = {};
#pragma unroll
    for (int nb = 0; nb < 4; nb++) {
      short8 bk0 = *(const short8*)&Ks[nb * 16 + l16][cs0];
      short8 bk1 = *(const short8*)&Ks[nb * 16 + l16][cs1];
      s[nb] = __builtin_amdgcn_mfma_f32_16x16x32_bf16(aq0, bk0, s[nb], 0, 0, 0);
      s[nb] = __builtin_amdgcn_mfma_f32_16x16x32_bf16(aq1, bk1, s[nb], 0, 0, 0);
    }

    if (jt == qt) {   // causal mask, diagonal tile only
#pragma unroll
      for (int nb = 0; nb < 4; nb++) {
        int col = nb * 16 + l16;
#pragma unroll
        for (int r = 0; r < 4; r++)
          if (col > wid * 16 + quad * 4 + r) s[nb][r] = -INFINITY;
      }
    }

    // ---- p = exp2(s); per-lane l partials; write P (wave-private Ps: no barrier)
#pragma unroll
    for (int r = 0; r < 4; r++) {
#pragma unroll
      for (int nb = 0; nb < 4; nb++) {
        float p = __builtin_amdgcn_exp2f(s[nb][r]);
        lsum[r] += p;
        psf[pwo[r][nb]] = (short)f2bf(p);
      }
    }

    // ---- O += P @ V (compiler inserts lgkmcnt wait for Ps round-trip)
    short8 ap0 = *(const short8*)&Ps[wid][l16][cs0];
    short8 ap1 = *(const short8*)&Ps[wid][l16][cs1];
#pragma unroll
    for (int nb = 0; nb < 4; nb++) {
      short8 bv0 = *(const short8*)&Vs[nb * 16 + l16][cs0];
      short8 bv1 = *(const short8*)&Vs[nb * 16 + l16][cs1];
      acc_o[nb] = __builtin_amdgcn_mfma_f32_16x16x32_bf16(ap0, bv0, acc_o[nb], 0, 0, 0);
      acc_o[nb] = __builtin_amdgcn_mfma_f32_16x16x32_bf16(ap1, bv1, acc_o[nb], 0, 0, 0);
    }
    __syncthreads();   // protect Ks/Vs before next staging
  }

  if (direct) {
    // ---- epilogue: reduce l, normalize, v-orthogonalize (diag V still in Vs)
#pragma unroll
    for (int r = 0; r < 4; r++) {
      float ls = lsum[r];
#pragma unroll
      for (int off = 1; off < 16; off <<= 1) ls += __shfl_xor(ls, off);
      const float invl = 1.f / ls;

      const int rowl = wid * 16 + quad * 4 + r;
      const int vcol = ((rowl >> 3) ^ lo8) * 8 + (rowl & 7);   // swizzled t index
      float vd[4], dot = 0.f, vv = 0.f;
#pragma unroll
      for (int nb = 0; nb < 4; nb++) {
        vd[nb] = bf2f((unsigned short)Vs[nb * 16 + l16][vcol]);
        dot += acc_o[nb][r] * invl * vd[nb];
        vv  += vd[nb] * vd[nb];
      }
#pragma unroll
      for (int off = 1; off < 16; off <<= 1) {
        dot += __shfl_xor(dot, off);
        vv  += __shfl_xor(vv, off);
      }
      const float coef = dot / fmaxf(vv, 1e-8f);
      unsigned short* dst = aob + ((size_t)(b * NT + qt * 64 + rowl)) * ND + h * HDIM + l16;
#pragma unroll
      for (int nb = 0; nb < 4; nb++)
        dst[nb * 16] = f2bf(acc_o[nb][r] * invl - coef * vd[nb]);
    }
  } else {
    // ---- write partial O (unnormalized) + partial l
    const int slot = ((b * NHEADS + h) * 16 + (qt - 16)) * 2 + chunk;
    float* pO = pbuf + (size_t)slot * 4160;
    float* pl = pO + 4096;
#pragma unroll
    for (int r = 0; r < 4; r++) {
      float ls = lsum[r];
#pragma unroll
      for (int off = 1; off < 16; off <<= 1) ls += __shfl_xor(ls, off);
      const int rowl = wid * 16 + quad * 4 + r;
      if (l16 == 0) pl[rowl] = ls;
#pragma unroll
      for (int nb = 0; nb < 4; nb++)
        pO[rowl * 64 + nb * 16 + l16] = acc_o[nb][r];
    }
  }
}

// --------------- reduction for qt>=16: sum 2 partials, normalize, v-orth, store
// Grid (16, NH, NB), 256 threads: thread = (row = tid>>2, dq = tid&3 owns 16 d).
__global__ __launch_bounds__(256) void redn(
    const float* __restrict__ pbuf,
    const unsigned short* __restrict__ vtb,
    unsigned short* __restrict__ aob)
{
  const int qt = 16 + blockIdx.x;
  const int h = blockIdx.y, b = blockIdx.z;
  const int kv = h >> 2;
  const int tid = threadIdx.x;

  const int slot0 = ((b * NHEADS + h) * 16 + blockIdx.x) * 2;
  const float* O0 = pbuf + (size_t)slot0 * 4160;
  const float* O1 = O0 + 4160;
  const float* l0 = O0 + 4096;
  const float* l1 = O1 + 4096;

  __shared__ short vt[64][66];   // [d][t_local]

  // stage V tile (v at t = qt*64 + row)
  {
    const int d = tid >> 2, tq = (tid & 3) * 16;
    const unsigned short* src = vtb + ((size_t)((b * NKVH + kv) * HDIM + d)) * NT + qt * 64 + tq;
    short8 v0 = *(const short8*)src;
    short8 v1 = *(const short8*)(src + 8);
    *(short8*)&vt[d][tq] = v0;
    *(short8*)&vt[d][tq + 8] = v1;
  }
  __syncthreads();

  const int row = tid >> 2, dq = tid & 3;
  const float invl = 1.f / (l0[row] + l1[row]);

  float o[16], vd[16];
  float dot = 0.f, vv = 0.f;
#pragma unroll
  for (int j = 0; j < 16; j++) {
    const int d = dq * 16 + j;
    float ov = (O0[row * 64 + d] + O1[row * 64 + d]) * invl;
    float v  = bf2f((unsigned short)vt[d][row]);
    o[j] = ov; vd[j] = v;
    dot += ov * v; vv += v * v;
  }
  // reduce across the 4 lanes sharing this row (lanes row*4+dq within a wave)
  dot += __shfl_xor(dot, 1); dot += __shfl_xor(dot, 2);
  vv  += __shfl_xor(vv, 1);  vv  += __shfl_xor(vv, 2);
  const float coef = dot / fmaxf(vv, 1e-8f);

  unsigned short* dst = aob + ((size_t)(b * NT + qt * 64 + row)) * ND + h * HDIM + dq * 16;
  ushort4 w0, w1, w2, w3;
  w0.x = f2bf(o[0] - coef * vd[0]);  w0.y = f2bf(o[1] - coef * vd[1]);
  w0.z = f2bf(o[2] - coef * vd[2]);  w0.w = f2bf(o[3] - coef * vd[3]);
  w1.x = f2bf(o[4] - coef * vd[4]);  w1.y = f2bf(o[5] - coef * vd[5]);
  w1.z = f2bf(o[6] - coef * vd[6]);  w1.w = f2bf(o[7] - coef * vd[7]);
  w2.x = f2bf(o[8] - coef * vd[8]);  w2.y = f2bf(o[9] - coef * vd[9]);
  w2.z = f2bf(o[10] - coef * vd[10]); w2.w = f2bf(o[11] - coef * vd[11]);
  w3.x = f2bf(o[12] - coef * vd[12]); w3.y = f2bf(o[13] - coef * vd[13]);
  w3.z = f2bf(o[14] - coef * vd[14]); w3.w = f2bf(o[15] - coef * vd[15]);
  ((ushort4*)dst)[0] = w0; ((ushort4*)dst)[1] = w1;
  ((ushort4*)dst)[2] = w2; ((ushort4*)dst)[3] = w3;
}

// ---------------------------------------------------------------------- launch
extern "C" void kernel_launch(void* const* d_in, const int* in_sizes, int n_in,
                              void* d_out, int out_size, void* d_ws, size_t ws_size,
                              hipStream_t stream) {
  const float* x       = (const float*)d_in[0];
  const float* cosT    = (const float*)d_in[1];
  const float* sinT    = (const float*)d_in[2];
  const float* w_qkv   = (const float*)d_in[4];
  const float* w_out   = (const float*)d_in[5];
  const float* q_scale = (const float*)d_in[6];
  const float* k_scale = (const float*)d_in[7];
  float* out = (float*)d_out;

  char* ws = (char*)d_ws;
  unsigned short* xb    = (unsigned short*)ws;                         // 8 MB
  unsigned short* qb    = xb;                                          // overlay
  unsigned short* wqkvb = (unsigned short*)(ws + 8388608);             // 3 MB
  unsigned short* kb    = wqkvb;                                       // overlay (2 MB)
  unsigned short* woutb = (unsigned short*)(ws + 11534336);            // 2 MB
  float*          qkv   = (float*)(ws + 13631488);                     // 25.2 MB fp32
  float*          pbuf  = qkv;                                         // overlay (17 MB, qkv dead)
  unsigned short* vtb   = (unsigned short*)(ws + 38797312);            // 2 MB
  unsigned short* aob   = (unsigned short*)(ws + 40894464);            // 8 MB (ends 47 MiB)

  cvt_bf16<<<(NB * NT * ND / 4 + 255) / 256, 256, 0, stream>>>(x, xb, NB * NT * ND / 4);
  cvt_bf16<<<(QKVD * ND / 4 + 255) / 256, 256, 0, stream>>>(w_qkv, wqkvb, QKVD * ND / 4);
  cvt_bf16<<<(ND * ND / 4 + 255) / 256, 256, 0, stream>>>(w_out, woutb, ND * ND / 4);

  // qkv = x @ w_qkv^T   (M=4096, N=1536, K=1024)
  gemm12864<<<dim3(NB * NT / 128, QKVD / 64), 256, 0, stream>>>(
      xb, wqkvb, qkv, NB * NT, QKVD, ND);

  rope_pack<<<dim3(NT / 8, 5, NB), 256, 0, stream>>>(qkv, cosT, sinT, q_scale, k_scale, qb, kb);
  vT<<<dim3(NT / 64, NKVH, NB), 256, 0, stream>>>(qkv, vtb);

  fattn<<<dim3(48, NHEADS, NB), 256, 0, stream>>>(qb, kb, vtb, aob, pbuf);
  redn<<<dim3(16, NHEADS, NB), 256, 0, stream>>>(pbuf, vtb, aob);

  // out = ao @ w_out^T   (M=4096, N=1024, K=1024)
  gemm12864<<<dim3(NB * NT / 128, ND / 64), 256, 0, stream>>>(
      aob, woutb, out, NB * NT, ND, ND);
}

// Round 5
// 216.211 us; speedup vs baseline: 14.9673x; 1.0182x over previous
//
#include <hip/hip_runtime.h>
#include <hip/hip_bf16.h>

#define NB 2
#define NT 2048
#define ND 1024
#define NHEADS 16
#define NKVH 4
#define HDIM 64
#define QKVD 1536   // (NHEADS + 2*NKVH) * HDIM

typedef __attribute__((ext_vector_type(8))) short short8;
typedef __attribute__((ext_vector_type(4))) float floatx4;

#if defined(__has_builtin)
#  if __has_builtin(__builtin_amdgcn_global_load_lds)
#    define HAS_GLL 1
#  endif
#endif
#ifndef HAS_GLL
#  define HAS_GLL 0
#endif

// async global->LDS, 16B per lane. l is the per-thread slot (= wave-uniform
// base + lane*16); HW uses firstlane(l) + lane*16 which is identical.
__device__ __forceinline__ void gll16(const void* g, void* l, int lane) {
#if HAS_GLL
  (void)lane;
  __builtin_amdgcn_global_load_lds(
      (const __attribute__((address_space(1))) unsigned int*)g,
      (__attribute__((address_space(3))) unsigned int*)l, 16, 0, 0);
#else
  *(short8*)((short*)l) = *(const short8*)g;
#endif
}

__device__ __forceinline__ unsigned short f2bf(float f) {
  union { float f; unsigned int u; } cv; cv.f = f;
  unsigned int u = cv.u;
  u += 0x7fffu + ((u >> 16) & 1u);   // round-to-nearest-even
  return (unsigned short)(u >> 16);
}
__device__ __forceinline__ float bf2f(unsigned short u) {
  union { unsigned int u; float f; } cv; cv.u = ((unsigned int)u) << 16; return cv.f;
}

// ---------------------------------------------------------------- converts
__global__ __launch_bounds__(256) void cvt_bf16(const float* __restrict__ in,
                                                unsigned short* __restrict__ out,
                                                int n4) {
  int i = blockIdx.x * 256 + threadIdx.x;
  if (i < n4) {
    float4 v = ((const float4*)in)[i];
    ushort4 o;
    o.x = f2bf(v.x); o.y = f2bf(v.y); o.z = f2bf(v.z); o.w = f2bf(v.w);
    ((ushort4*)out)[i] = o;
  }
}

// ------------- bf16 MFMA GEMM: C = A * B^T, 128x128, global_load_lds + dbuf
// 4 waves, each owns a 64x64 quadrant (4x4 frags). XOR swizzle done on the
// GLOBAL address side (gptr fetches logical chunk pc^(row&3)) so the LDS
// layout stays linear as global_load_lds requires; reads are 2-way max.
__global__ __launch_bounds__(256) void gemm_lds(
    const unsigned short* __restrict__ A,
    const unsigned short* __restrict__ Bm,
    float* __restrict__ C, int M, int N, int K)
{
  __shared__ __align__(16) short As[2][128][32];
  __shared__ __align__(16) short Bs[2][128][32];

  const int tid = threadIdx.x;
  const int wid = tid >> 6, lane = tid & 63;
  const int quad = lane >> 4, l16 = lane & 15;
  const int wm = (wid >> 1) * 64, wn = (wid & 1) * 64;
  const int m0 = blockIdx.x * 128, n0 = blockIdx.y * 128;

  const int r0 = tid >> 2;                       // staged row 0..63 (and +64)
  const int lc = ((tid & 3) ^ (r0 & 3)) * 8;     // logical chunk for this slot

  const unsigned short* ag0 = A  + (size_t)(m0 + r0) * K + lc;
  const unsigned short* ag1 = ag0 + (size_t)64 * K;
  const unsigned short* bg0 = Bm + (size_t)(n0 + r0) * K + lc;
  const unsigned short* bg1 = bg0 + (size_t)64 * K;

  short* asb = &As[0][0][0];
  short* bsb = &Bs[0][0][0];
  const int lofs = (HAS_GLL ? wid * 512 : tid * 8);  // shorts (slot for this thread/wave)

  const int cs = (quad ^ (l16 & 3)) * 8;         // swizzled frag column

  floatx4 acc[4][4] = {};

  // stage k-tile 0 into buffer 0
  gll16(ag0, asb + lofs, lane);
  gll16(ag1, asb + 2048 + lofs, lane);
  gll16(bg0, bsb + lofs, lane);
  gll16(bg1, bsb + 2048 + lofs, lane);

  const int NIT = K / 32;
  for (int it = 0; it < NIT; it++) {
    __syncthreads();                 // buf[it&1] ready; prev readers of buf[bn] done
    const int bi = it & 1, bn = bi ^ 1;
    if (it + 1 < NIT) {              // stage next tile; stays in flight over compute
      const int k = (it + 1) * 32;
      gll16(ag0 + k, asb + bn * 4096 + lofs, lane);
      gll16(ag1 + k, asb + bn * 4096 + 2048 + lofs, lane);
      gll16(bg0 + k, bsb + bn * 4096 + lofs, lane);
      gll16(bg1 + k, bsb + bn * 4096 + 2048 + lofs, lane);
    }

    short8 af[4], bf[4];
#pragma unroll
    for (int mi = 0; mi < 4; mi++) af[mi] = *(const short8*)&As[bi][wm + mi * 16 + l16][cs];
#pragma unroll
    for (int ni = 0; ni < 4; ni++) bf[ni] = *(const short8*)&Bs[bi][wn + ni * 16 + l16][cs];
#pragma unroll
    for (int mi = 0; mi < 4; mi++)
#pragma unroll
      for (int ni = 0; ni < 4; ni++)
        acc[mi][ni] = __builtin_amdgcn_mfma_f32_16x16x32_bf16(af[mi], bf[ni], acc[mi][ni], 0, 0, 0);
  }

#pragma unroll
  for (int mi = 0; mi < 4; mi++)
#pragma unroll
    for (int ni = 0; ni < 4; ni++)
#pragma unroll
      for (int r = 0; r < 4; r++) {
        int m = m0 + wm + mi * 16 + quad * 4 + r;
        int n = n0 + wn + ni * 16 + l16;
        C[(size_t)m * N + n] = acc[mi][ni][r];
      }
}

// ------------------- RoPE(first 16 dims) + head scales, pack to bf16 head-major
// q gets 0.125*log2(e)*q_scale folded in. Each block handles 8 t values.
__global__ __launch_bounds__(256) void rope_pack(
    const float* __restrict__ qkv,
    const float* __restrict__ cosT, const float* __restrict__ sinT,
    const float* __restrict__ q_scale, const float* __restrict__ k_scale,
    unsigned short* __restrict__ qb, unsigned short* __restrict__ kb)
{
  const int b  = blockIdx.z;
  const int hh = blockIdx.y * 4 + (threadIdx.x >> 6);  // 0..19
  const int d  = threadIdx.x & 63;

  float scale; int soff; unsigned short* dbase;
  if (hh < NHEADS) {
    scale = q_scale[hh] * (0.125f * 1.44269504088896f);
    soff = hh * HDIM;
    dbase = qb + ((size_t)(b * NHEADS + hh) * NT) * HDIM;
  } else {
    int kvh = hh - NHEADS;
    scale = k_scale[kvh];
    soff = NHEADS * HDIM + kvh * HDIM;
    dbase = kb + ((size_t)(b * NKVH + kvh) * NT) * HDIM;
  }

  for (int i = 0; i < 8; i++) {
    const int t = blockIdx.x * 8 + i;
    const float* src = qkv + ((size_t)(b * NT + t)) * QKVD + soff;
    float out;
    if (d < 8) {
      float x1 = src[d], x2 = src[d + 8];
      float c = cosT[t * 8 + d], s = sinT[t * 8 + d];
      out = (x1 * c - x2 * s) * scale;
    } else if (d < 16) {
      float x1 = src[d - 8], x2 = src[d];
      float c = cosT[t * 8 + d - 8], s = sinT[t * 8 + d - 8];
      out = (x1 * s + x2 * c) * scale;
    } else {
      out = src[d] * scale;
    }
    dbase[(size_t)t * HDIM + d] = f2bf(out);
  }
}

// -------------------------------- transpose V to bf16 [B][NKV][HD][T] for fattn
__global__ __launch_bounds__(256) void vT(const float* __restrict__ qkv,
                                          unsigned short* __restrict__ vtb)
{
  const int tt  = blockIdx.x;
  const int kvh = blockIdx.y;
  const int b   = blockIdx.z;
  const int tid = threadIdx.x;

  __shared__ float tile[64][65];

  {
    const int tl = tid >> 2, d0 = (tid & 3) * 16;
    const float* src = qkv + ((size_t)(b * NT + tt * 64 + tl)) * QKVD
                       + (NHEADS + NKVH) * HDIM + kvh * HDIM + d0;
#pragma unroll
    for (int j = 0; j < 16; j += 4) {
      float4 v = *(const float4*)(src + j);
      tile[tl][d0 + j + 0] = v.x; tile[tl][d0 + j + 1] = v.y;
      tile[tl][d0 + j + 2] = v.z; tile[tl][d0 + j + 3] = v.w;
    }
  }
  __syncthreads();
  {
    const int dd = tid >> 2, t0 = (tid & 3) * 16;
    unsigned short* dst = vtb + ((size_t)((b * NKVH + kvh) * HDIM + dd)) * NT + tt * 64 + t0;
#pragma unroll
    for (int j = 0; j < 16; j++) dst[j] = f2bf(tile[t0 + j][dd]);
  }
}

// ----------------------------------------------------- flash attention (MFMA)
// Fixed-m base-2 softmax (additive partials), uniform KV-chunking (as r4).
// global_load_lds staging, double-buffered K/V, ONE barrier per iteration.
__global__ __launch_bounds__(256) void fattn(
    const unsigned short* __restrict__ qb,   // [B][NH][T][64]
    const unsigned short* __restrict__ kb,   // [B][NKV][T][64]
    const unsigned short* __restrict__ vtb,  // [B][NKV][64][T]
    unsigned short* __restrict__ aob,        // [B][T][NH*64]
    float* __restrict__ pbuf)                // 1024 slots x (64*64 O + 64 l) fp32
{
  const int idx = blockIdx.x;
  const int h = blockIdx.y, b = blockIdx.z;
  const int kv = h >> 2;

  int qt, j0, cnt, chunk; bool direct;
  if (idx < 16) { qt = 16 + idx; j0 = 0; cnt = 16; chunk = 0; direct = false; }
  else {
    int rel = idx - 16, s = 16 - (rel >> 1);
    if ((rel & 1) == 0) { qt = s - 1;  j0 = 0;  cnt = s; chunk = 0; direct = true;  }
    else                { qt = s + 15; j0 = 16; cnt = s; chunk = 1; direct = false; }
  }

  const int tid = threadIdx.x;
  const int wid = tid >> 6, lane = tid & 63;
  const int quad = lane >> 4, l16 = lane & 15;
  const int hi8 = l16 >> 3, lo8 = l16 & 7;

  __shared__ __align__(16) short Ks[2][64][64];   // [t][d], chunk^(t&7) via gptr
  __shared__ __align__(16) short Vs[2][64][64];   // [d][t], chunk^(d&7) via gptr
  __shared__ __align__(16) short Ps[4][16][64];   // [wave][q][t], chunk^(q&7)

  // ---- Q fragments straight from global
  const unsigned short* qg = qb + ((size_t)((b * NHEADS + h) * NT + qt * 64)) * HDIM;
  const int qrow = wid * 16 + l16;
  short8 aq0 = *(const short8*)(qg + (size_t)qrow * HDIM + quad * 8);
  short8 aq1 = *(const short8*)(qg + (size_t)qrow * HDIM + 32 + quad * 8);

  // ---- global_load_lds staging geometry (gptr-side swizzle)
  const int sr  = tid >> 3;                        // LDS row 0..31 (and +32)
  const int lck = ((tid & 7) ^ (sr & 7)) * 8;      // logical chunk for this slot
  const unsigned short* kgp0 = kb  + ((size_t)((b * NKVH + kv) * NT) + sr) * HDIM + lck;
  const unsigned short* vgp0 = vtb + ((size_t)((b * NKVH + kv) * HDIM) + sr) * NT + lck;
  short* ksb = &Ks[0][0][0];
  short* vsb = &Vs[0][0][0];
  const int lofs = (HAS_GLL ? wid * 512 : tid * 8);  // shorts

  // ---- fragment-read swizzled column offsets
  const int cs0 = (quad ^ lo8) * 8;
  const int cs1 = cs0 ^ 32;

  // ---- P write offsets, loop-invariant
  int pwo[4][4];
#pragma unroll
  for (int r = 0; r < 4; r++) {
    const int row = quad * 4 + r;
#pragma unroll
    for (int nb = 0; nb < 4; nb++)
      pwo[r][nb] = wid * 1024 + row * 64 + (((nb * 2 + hi8) ^ (row & 7)) * 8) + lo8;
  }
  short* psf = &Ps[0][0][0];

  floatx4 acc_o[4] = {};
  float lsum[4] = {0.f, 0.f, 0.f, 0.f};

  // ---- stage first tile into buffer 0
  {
    const unsigned short* kg = kgp0 + (size_t)j0 * 64 * HDIM;
    const unsigned short* vg = vgp0 + j0 * 64;
    gll16(kg, ksb + lofs, lane);
    gll16(kg + 32 * HDIM, ksb + 2048 + lofs, lane);
    gll16(vg, vsb + lofs, lane);
    gll16(vg + (size_t)32 * NT, vsb + 2048 + lofs, lane);
  }

  for (int i = 0; i < cnt; i++) {
    const int jt = j0 + i;
    __syncthreads();                 // buf[i&1] ready; readers of buf[bn] done
    const int bi = i & 1, bn = bi ^ 1;
    if (i + 1 < cnt) {               // stage next tile; in flight over compute
      const unsigned short* kg = kgp0 + (size_t)(jt + 1) * 64 * HDIM;
      const unsigned short* vg = vgp0 + (jt + 1) * 64;
      gll16(kg, ksb + bn * 4096 + lofs, lane);
      gll16(kg + 32 * HDIM, ksb + bn * 4096 + 2048 + lofs, lane);
      gll16(vg, vsb + bn * 4096 + lofs, lane);
      gll16(vg + (size_t)32 * NT, vsb + bn * 4096 + 2048 + lofs, lane);
    }

    // ---- S = Q @ K^T
    floatx4 s[4] = {};
#pragma unroll
    for (int nb = 0; nb < 4; nb++) {
      short8 bk0 = *(const short8*)&Ks[bi][nb * 16 + l16][cs0];
      short8 bk1 = *(const short8*)&Ks[bi][nb * 16 + l16][cs1];
      s[nb] = __builtin_amdgcn_mfma_f32_16x16x32_bf16(aq0, bk0, s[nb], 0, 0, 0);
      s[nb] = __builtin_amdgcn_mfma_f32_16x16x32_bf16(aq1, bk1, s[nb], 0, 0, 0);
    }

    if (jt == qt) {   // causal mask, diagonal tile only
#pragma unroll
      for (int nb = 0; nb < 4; nb++) {
        int col = nb * 16 + l16;
#pragma unroll
        for (int r = 0; r < 4; r++)
          if (col > wid * 16 + quad * 4 + r) s[nb][r] = -INFINITY;
      }
    }

    // ---- p = exp2(s); per-lane l partials; write P (truncation-convert: 1 VALU)
#pragma unroll
    for (int r = 0; r < 4; r++) {
#pragma unroll
      for (int nb = 0; nb < 4; nb++) {
        float p = __builtin_amdgcn_exp2f(s[nb][r]);
        lsum[r] += p;
        psf[pwo[r][nb]] = (short)(__float_as_uint(p) >> 16);
      }
    }

    // ---- O += P @ V (wave-local Ps round-trip; lgkm wait only)
    short8 ap0 = *(const short8*)&Ps[wid][l16][cs0];
    short8 ap1 = *(const short8*)&Ps[wid][l16][cs1];
#pragma unroll
    for (int nb = 0; nb < 4; nb++) {
      short8 bv0 = *(const short8*)&Vs[bi][nb * 16 + l16][cs0];
      short8 bv1 = *(const short8*)&Vs[bi][nb * 16 + l16][cs1];
      acc_o[nb] = __builtin_amdgcn_mfma_f32_16x16x32_bf16(ap0, bv0, acc_o[nb], 0, 0, 0);
      acc_o[nb] = __builtin_amdgcn_mfma_f32_16x16x32_bf16(ap1, bv1, acc_o[nb], 0, 0, 0);
    }
  }

  const int bl = (cnt - 1) & 1;      // buffer holding the last (diagonal) tile

  if (direct) {
    // ---- epilogue: reduce l, normalize, v-orthogonalize (diag V still in Vs[bl])
#pragma unroll
    for (int r = 0; r < 4; r++) {
      float ls = lsum[r];
#pragma unroll
      for (int off = 1; off < 16; off <<= 1) ls += __shfl_xor(ls, off);
      const float invl = 1.f / ls;

      const int rowl = wid * 16 + quad * 4 + r;
      const int vcol = ((rowl >> 3) ^ lo8) * 8 + (rowl & 7);   // swizzled t index
      float vd[4], dot = 0.f, vv = 0.f;
#pragma unroll
      for (int nb = 0; nb < 4; nb++) {
        vd[nb] = bf2f((unsigned short)Vs[bl][nb * 16 + l16][vcol]);
        dot += acc_o[nb][r] * invl * vd[nb];
        vv  += vd[nb] * vd[nb];
      }
#pragma unroll
      for (int off = 1; off < 16; off <<= 1) {
        dot += __shfl_xor(dot, off);
        vv  += __shfl_xor(vv, off);
      }
      const float coef = dot / fmaxf(vv, 1e-8f);
      unsigned short* dst = aob + ((size_t)(b * NT + qt * 64 + rowl)) * ND + h * HDIM + l16;
#pragma unroll
      for (int nb = 0; nb < 4; nb++)
        dst[nb * 16] = f2bf(acc_o[nb][r] * invl - coef * vd[nb]);
    }
  } else {
    // ---- write partial O (unnormalized) + partial l
    const int slot = ((b * NHEADS + h) * 16 + (qt - 16)) * 2 + chunk;
    float* pO = pbuf + (size_t)slot * 4160;
    float* pl = pO + 4096;
#pragma unroll
    for (int r = 0; r < 4; r++) {
      float ls = lsum[r];
#pragma unroll
      for (int off = 1; off < 16; off <<= 1) ls += __shfl_xor(ls, off);
      const int rowl = wid * 16 + quad * 4 + r;
      if (l16 == 0) pl[rowl] = ls;
#pragma unroll
      for (int nb = 0; nb < 4; nb++)
        pO[rowl * 64 + nb * 16 + l16] = acc_o[nb][r];
    }
  }
}

// --------------- reduction for qt>=16: sum 2 partials, normalize, v-orth, store
__global__ __launch_bounds__(256) void redn(
    const float* __restrict__ pbuf,
    const unsigned short* __restrict__ vtb,
    unsigned short* __restrict__ aob)
{
  const int qt = 16 + blockIdx.x;
  const int h = blockIdx.y, b = blockIdx.z;
  const int kv = h >> 2;
  const int tid = threadIdx.x;

  const int slot0 = ((b * NHEADS + h) * 16 + blockIdx.x) * 2;
  const float* O0 = pbuf + (size_t)slot0 * 4160;
  const float* O1 = O0 + 4160;
  const float* l0 = O0 + 4096;
  const float* l1 = O1 + 4096;

  __shared__ short vt[64][66];   // [d][t_local]

  {
    const int d = tid >> 2, tq = (tid & 3) * 16;
    const unsigned short* src = vtb + ((size_t)((b * NKVH + kv) * HDIM + d)) * NT + qt * 64 + tq;
    short8 v0 = *(const short8*)src;
    short8 v1 = *(const short8*)(src + 8);
    *(short8*)&vt[d][tq] = v0;
    *(short8*)&vt[d][tq + 8] = v1;
  }
  __syncthreads();

  const int row = tid >> 2, dq = tid & 3;
  const float invl = 1.f / (l0[row] + l1[row]);

  float o[16], vd[16];
  float dot = 0.f, vv = 0.f;
#pragma unroll
  for (int j = 0; j < 16; j++) {
    const int d = dq * 16 + j;
    float ov = (O0[row * 64 + d] + O1[row * 64 + d]) * invl;
    float v  = bf2f((unsigned short)vt[d][row]);
    o[j] = ov; vd[j] = v;
    dot += ov * v; vv += v * v;
  }
  dot += __shfl_xor(dot, 1); dot += __shfl_xor(dot, 2);
  vv  += __shfl_xor(vv, 1);  vv  += __shfl_xor(vv, 2);
  const float coef = dot / fmaxf(vv, 1e-8f);

  unsigned short* dst = aob + ((size_t)(b * NT + qt * 64 + row)) * ND + h * HDIM + dq * 16;
  ushort4 w0, w1, w2, w3;
  w0.x = f2bf(o[0] - coef * vd[0]);  w0.y = f2bf(o[1] - coef * vd[1]);
  w0.z = f2bf(o[2] - coef * vd[2]);  w0.w = f2bf(o[3] - coef * vd[3]);
  w1.x = f2bf(o[4] - coef * vd[4]);  w1.y = f2bf(o[5] - coef * vd[5]);
  w1.z = f2bf(o[6] - coef * vd[6]);  w1.w = f2bf(o[7] - coef * vd[7]);
  w2.x = f2bf(o[8] - coef * vd[8]);  w2.y = f2bf(o[9] - coef * vd[9]);
  w2.z = f2bf(o[10] - coef * vd[10]); w2.w = f2bf(o[11] - coef * vd[11]);
  w3.x = f2bf(o[12] - coef * vd[12]); w3.y = f2bf(o[13] - coef * vd[13]);
  w3.z = f2bf(o[14] - coef * vd[14]); w3.w = f2bf(o[15] - coef * vd[15]);
  ((ushort4*)dst)[0] = w0; ((ushort4*)dst)[1] = w1;
  ((ushort4*)dst)[2] = w2; ((ushort4*)dst)[3] = w3;
}

// ---------------------------------------------------------------------- launch
extern "C" void kernel_launch(void* const* d_in, const int* in_sizes, int n_in,
                              void* d_out, int out_size, void* d_ws, size_t ws_size,
                              hipStream_t stream) {
  const float* x       = (const float*)d_in[0];
  const float* cosT    = (const float*)d_in[1];
  const float* sinT    = (const float*)d_in[2];
  const float* w_qkv   = (const float*)d_in[4];
  const float* w_out   = (const float*)d_in[5];
  const float* q_scale = (const float*)d_in[6];
  const float* k_scale = (const float*)d_in[7];
  float* out = (float*)d_out;

  char* ws = (char*)d_ws;
  unsigned short* xb    = (unsigned short*)ws;                         // 8 MB
  unsigned short* qb    = xb;                                          // overlay
  unsigned short* wqkvb = (unsigned short*)(ws + 8388608);             // 3 MB
  unsigned short* kb    = wqkvb;                                       // overlay (2 MB)
  unsigned short* woutb = (unsigned short*)(ws + 11534336);            // 2 MB
  float*          qkv   = (float*)(ws + 13631488);                     // 25.2 MB fp32
  float*          pbuf  = qkv;                                         // overlay (17 MB, qkv dead)
  unsigned short* vtb   = (unsigned short*)(ws + 38797312);            // 2 MB
  unsigned short* aob   = (unsigned short*)(ws + 40894464);            // 8 MB

  cvt_bf16<<<(NB * NT * ND / 4 + 255) / 256, 256, 0, stream>>>(x, xb, NB * NT * ND / 4);
  cvt_bf16<<<(QKVD * ND / 4 + 255) / 256, 256, 0, stream>>>(w_qkv, wqkvb, QKVD * ND / 4);
  cvt_bf16<<<(ND * ND / 4 + 255) / 256, 256, 0, stream>>>(w_out, woutb, ND * ND / 4);

  // qkv = x @ w_qkv^T   (M=4096, N=1536, K=1024)
  gemm_lds<<<dim3(NB * NT / 128, QKVD / 128), 256, 0, stream>>>(
      xb, wqkvb, qkv, NB * NT, QKVD, ND);

  rope_pack<<<dim3(NT / 8, 5, NB), 256, 0, stream>>>(qkv, cosT, sinT, q_scale, k_scale, qb, kb);
  vT<<<dim3(NT / 64, NKVH, NB), 256, 0, stream>>>(qkv, vtb);

  fattn<<<dim3(48, NHEADS, NB), 256, 0, stream>>>(qb, kb, vtb, aob, pbuf);
  redn<<<dim3(16, NHEADS, NB), 256, 0, stream>>>(pbuf, vtb, aob);

  // out = ao @ w_out^T   (M=4096, N=1024, K=1024)
  gemm_lds<<<dim3(NB * NT / 128, ND / 128), 256, 0, stream>>>(
      aob, woutb, out, NB * NT, ND, ND);
}

// Round 6
// 195.156 us; speedup vs baseline: 16.5820x; 1.1079x over previous
//
#include <hip/hip_runtime.h>
#include <hip/hip_bf16.h>

#define NB 2
#define NT 2048
#define ND 1024
#define NHEADS 16
#define NKVH 4
#define HDIM 64
#define QKVD 1536   // (NHEADS + 2*NKVH) * HDIM

typedef __attribute__((ext_vector_type(8))) short short8;
typedef __attribute__((ext_vector_type(4))) float floatx4;

#if defined(__has_builtin)
#  if __has_builtin(__builtin_amdgcn_global_load_lds)
#    define HAS_GLL 1
#  endif
#endif
#ifndef HAS_GLL
#  define HAS_GLL 0
#endif

// async global->LDS, 16B per lane. l is the per-thread slot (= wave-uniform
// base + lane*16); HW uses firstlane(l) + lane*16 which is identical.
__device__ __forceinline__ void gll16(const void* g, void* l, int lane) {
#if HAS_GLL
  (void)lane;
  __builtin_amdgcn_global_load_lds(
      (const __attribute__((address_space(1))) unsigned int*)g,
      (__attribute__((address_space(3))) unsigned int*)l, 16, 0, 0);
#else
  *(short8*)((short*)l) = *(const short8*)g;
#endif
}

__device__ __forceinline__ unsigned short f2bf(float f) {
  union { float f; unsigned int u; } cv; cv.f = f;
  unsigned int u = cv.u;
  u += 0x7fffu + ((u >> 16) & 1u);   // round-to-nearest-even
  return (unsigned short)(u >> 16);
}
__device__ __forceinline__ float bf2f(unsigned short u) {
  union { unsigned int u; float f; } cv; cv.u = ((unsigned int)u) << 16; return cv.f;
}

// ------------------------------------------- one fused fp32->bf16 convert pass
#define N4_X   1048576   // NB*NT*ND/4
#define N4_WQ   393216   // QKVD*ND/4
#define N4_WO   262144   // ND*ND/4
__global__ __launch_bounds__(256) void cvt_all(
    const float* __restrict__ x, const float* __restrict__ wq,
    const float* __restrict__ wo,
    unsigned short* __restrict__ xb, unsigned short* __restrict__ wqb,
    unsigned short* __restrict__ wob) {
  int i = blockIdx.x * 256 + threadIdx.x;
  const float* src; unsigned short* dst; int j;
  if (i < N4_X)              { src = x;  dst = xb;  j = i; }
  else if (i < N4_X + N4_WQ) { src = wq; dst = wqb; j = i - N4_X; }
  else                       { src = wo; dst = wob; j = i - N4_X - N4_WQ; }
  float4 v = ((const float4*)src)[j];
  ushort4 o;
  o.x = f2bf(v.x); o.y = f2bf(v.y); o.z = f2bf(v.z); o.w = f2bf(v.w);
  ((ushort4*)dst)[j] = o;
}

// ---------------- QKV GEMM with fused rope/scale/pack epilogue --------------
// C = xb @ wqkvb^T (M=4096, N=1536, K=1024), 128x128 tile, GLL + dbuf.
// Wave quadrant = 64 rows x 64 cols = one full head slice:
//   hh = blockIdx.y*2 + (wid&1); hh<16 -> q (rope+0.125*log2e*q_scale),
//   16..19 -> k (rope+k_scale), 20..23 -> v (written TRANSPOSED to vtb).
__global__ __launch_bounds__(256) void gemm_qkv(
    const unsigned short* __restrict__ A,
    const unsigned short* __restrict__ Bm,
    const float* __restrict__ cosT, const float* __restrict__ sinT,
    const float* __restrict__ q_scale, const float* __restrict__ k_scale,
    unsigned short* __restrict__ qb, unsigned short* __restrict__ kb,
    unsigned short* __restrict__ vtb)
{
  const int M = NB * NT, N = QKVD, K = ND;
  __shared__ __align__(16) short As[2][128][32];
  __shared__ __align__(16) short Bs[2][128][32];

  const int tid = threadIdx.x;
  const int wid = tid >> 6, lane = tid & 63;
  const int quad = lane >> 4, l16 = lane & 15;
  const int lo8 = l16 & 7;
  const int wm = (wid >> 1) * 64, wn = (wid & 1) * 64;
  const int m0 = blockIdx.x * 128, n0 = blockIdx.y * 128;

  const int r0 = tid >> 2;
  const int lc = ((tid & 3) ^ (r0 & 3)) * 8;

  const unsigned short* ag0 = A  + (size_t)(m0 + r0) * K + lc;
  const unsigned short* ag1 = ag0 + (size_t)64 * K;
  const unsigned short* bg0 = Bm + (size_t)(n0 + r0) * K + lc;
  const unsigned short* bg1 = bg0 + (size_t)64 * K;

  short* asb = &As[0][0][0];
  short* bsb = &Bs[0][0][0];
  const int lofs = (HAS_GLL ? wid * 512 : tid * 8);
  const int cs = (quad ^ (l16 & 3)) * 8;

  floatx4 acc[4][4] = {};

  gll16(ag0, asb + lofs, lane);
  gll16(ag1, asb + 2048 + lofs, lane);
  gll16(bg0, bsb + lofs, lane);
  gll16(bg1, bsb + 2048 + lofs, lane);

  const int NIT = K / 32;
  for (int it = 0; it < NIT; it++) {
    __syncthreads();
    const int bi = it & 1, bn = bi ^ 1;
    if (it + 1 < NIT) {
      const int k = (it + 1) * 32;
      gll16(ag0 + k, asb + bn * 4096 + lofs, lane);
      gll16(ag1 + k, asb + bn * 4096 + 2048 + lofs, lane);
      gll16(bg0 + k, bsb + bn * 4096 + lofs, lane);
      gll16(bg1 + k, bsb + bn * 4096 + 2048 + lofs, lane);
    }
    short8 af[4], bf[4];
#pragma unroll
    for (int mi = 0; mi < 4; mi++) af[mi] = *(const short8*)&As[bi][wm + mi * 16 + l16][cs];
#pragma unroll
    for (int ni = 0; ni < 4; ni++) bf[ni] = *(const short8*)&Bs[bi][wn + ni * 16 + l16][cs];
#pragma unroll
    for (int mi = 0; mi < 4; mi++)
#pragma unroll
      for (int ni = 0; ni < 4; ni++)
        acc[mi][ni] = __builtin_amdgcn_mfma_f32_16x16x32_bf16(af[mi], bf[ni], acc[mi][ni], 0, 0, 0);
  }

  // ------------------------------- fused epilogue -------------------------
  const int hh = blockIdx.y * 2 + (wid & 1);   // head slice 0..23

  if (hh >= NHEADS + NKVH) {
    // ---- v: write transposed bf16 to vtb[(b*NKV+kvh)*64 + d][t]
    const int kvh = hh - (NHEADS + NKVH);
#pragma unroll
    for (int mi = 0; mi < 4; mi++) {
      const int mrow = m0 + wm + mi * 16 + quad * 4;
      const int bb = mrow >> 11, tt = mrow & (NT - 1);
#pragma unroll
      for (int ni = 0; ni < 4; ni++) {
        const int d = ni * 16 + l16;
        ushort4 w;
        w.x = f2bf(acc[mi][ni][0]); w.y = f2bf(acc[mi][ni][1]);
        w.z = f2bf(acc[mi][ni][2]); w.w = f2bf(acc[mi][ni][3]);
        *(ushort4*)(vtb + ((size_t)((bb * NKVH + kvh) * HDIM + d)) * NT + tt) = w;
      }
    }
  } else {
    // ---- q/k: rope on first 16 dims (ni==0), scale, write head-major bf16
    float scl; unsigned short* dst0; int hloc;
    if (hh < NHEADS) { scl = q_scale[hh] * (0.125f * 1.44269504088896f); hloc = hh; dst0 = qb; }
    else             { scl = k_scale[hh - NHEADS];                        hloc = hh - NHEADS; dst0 = kb; }
    const int nh = (hh < NHEADS) ? NHEADS : NKVH;
#pragma unroll
    for (int mi = 0; mi < 4; mi++) {
#pragma unroll
      for (int r = 0; r < 4; r++) {
        const int mrow = m0 + wm + mi * 16 + quad * 4 + r;
        const int bb = mrow >> 11, tt = mrow & (NT - 1);
        unsigned short* drow = dst0 + ((size_t)((bb * nh + hloc) * NT + tt)) * HDIM;

        // rope pair exchange: lanes l16 and l16^8 hold (d, d+-8) of ni==0
        const float own = acc[mi][0][r];
        const float oth = __shfl_xor(own, 8);
        const float c = cosT[tt * 8 + lo8], s = sinT[tt * 8 + lo8];
        const float roped = (l16 < 8) ? (own * c - oth * s)   // d = l16 < 8
                                      : (oth * s + own * c);  // d = l16 in 8..15
        drow[l16] = f2bf(roped * scl);
#pragma unroll
        for (int ni = 1; ni < 4; ni++)
          drow[ni * 16 + l16] = f2bf(acc[mi][ni][r] * scl);
      }
    }
  }
}

// ------------- generic bf16 MFMA GEMM: C = A * B^T (fp32 C), GLL + dbuf -----
__global__ __launch_bounds__(256) void gemm_lds(
    const unsigned short* __restrict__ A,
    const unsigned short* __restrict__ Bm,
    float* __restrict__ C, int M, int N, int K)
{
  __shared__ __align__(16) short As[2][128][32];
  __shared__ __align__(16) short Bs[2][128][32];

  const int tid = threadIdx.x;
  const int wid = tid >> 6, lane = tid & 63;
  const int quad = lane >> 4, l16 = lane & 15;
  const int wm = (wid >> 1) * 64, wn = (wid & 1) * 64;
  const int m0 = blockIdx.x * 128, n0 = blockIdx.y * 128;

  const int r0 = tid >> 2;
  const int lc = ((tid & 3) ^ (r0 & 3)) * 8;

  const unsigned short* ag0 = A  + (size_t)(m0 + r0) * K + lc;
  const unsigned short* ag1 = ag0 + (size_t)64 * K;
  const unsigned short* bg0 = Bm + (size_t)(n0 + r0) * K + lc;
  const unsigned short* bg1 = bg0 + (size_t)64 * K;

  short* asb = &As[0][0][0];
  short* bsb = &Bs[0][0][0];
  const int lofs = (HAS_GLL ? wid * 512 : tid * 8);
  const int cs = (quad ^ (l16 & 3)) * 8;

  floatx4 acc[4][4] = {};

  gll16(ag0, asb + lofs, lane);
  gll16(ag1, asb + 2048 + lofs, lane);
  gll16(bg0, bsb + lofs, lane);
  gll16(bg1, bsb + 2048 + lofs, lane);

  const int NIT = K / 32;
  for (int it = 0; it < NIT; it++) {
    __syncthreads();
    const int bi = it & 1, bn = bi ^ 1;
    if (it + 1 < NIT) {
      const int k = (it + 1) * 32;
      gll16(ag0 + k, asb + bn * 4096 + lofs, lane);
      gll16(ag1 + k, asb + bn * 4096 + 2048 + lofs, lane);
      gll16(bg0 + k, bsb + bn * 4096 + lofs, lane);
      gll16(bg1 + k, bsb + bn * 4096 + 2048 + lofs, lane);
    }
    short8 af[4], bf[4];
#pragma unroll
    for (int mi = 0; mi < 4; mi++) af[mi] = *(const short8*)&As[bi][wm + mi * 16 + l16][cs];
#pragma unroll
    for (int ni = 0; ni < 4; ni++) bf[ni] = *(const short8*)&Bs[bi][wn + ni * 16 + l16][cs];
#pragma unroll
    for (int mi = 0; mi < 4; mi++)
#pragma unroll
      for (int ni = 0; ni < 4; ni++)
        acc[mi][ni] = __builtin_amdgcn_mfma_f32_16x16x32_bf16(af[mi], bf[ni], acc[mi][ni], 0, 0, 0);
  }

#pragma unroll
  for (int mi = 0; mi < 4; mi++)
#pragma unroll
    for (int ni = 0; ni < 4; ni++)
#pragma unroll
      for (int r = 0; r < 4; r++) {
        int m = m0 + wm + mi * 16 + quad * 4 + r;
        int n = n0 + wn + ni * 16 + l16;
        C[(size_t)m * N + n] = acc[mi][ni][r];
      }
}

// ----------------------------------------------------- flash attention (MFMA)
// Fixed-m base-2 softmax (additive partials), uniform KV-chunking.
// global_load_lds staging, double-buffered K/V, ONE barrier per iteration.
__global__ __launch_bounds__(256) void fattn(
    const unsigned short* __restrict__ qb,   // [B][NH][T][64]
    const unsigned short* __restrict__ kb,   // [B][NKV][T][64]
    const unsigned short* __restrict__ vtb,  // [B][NKV][64][T]
    unsigned short* __restrict__ aob,        // [B][T][NH*64]
    float* __restrict__ pbuf)                // 1024 slots x (64*64 O + 64 l) fp32
{
  const int idx = blockIdx.x;
  const int h = blockIdx.y, b = blockIdx.z;
  const int kv = h >> 2;

  int qt, j0, cnt, chunk; bool direct;
  if (idx < 16) { qt = 16 + idx; j0 = 0; cnt = 16; chunk = 0; direct = false; }
  else {
    int rel = idx - 16, s = 16 - (rel >> 1);
    if ((rel & 1) == 0) { qt = s - 1;  j0 = 0;  cnt = s; chunk = 0; direct = true;  }
    else                { qt = s + 15; j0 = 16; cnt = s; chunk = 1; direct = false; }
  }

  const int tid = threadIdx.x;
  const int wid = tid >> 6, lane = tid & 63;
  const int quad = lane >> 4, l16 = lane & 15;
  const int hi8 = l16 >> 3, lo8 = l16 & 7;

  __shared__ __align__(16) short Ks[2][64][64];   // [t][d], chunk^(t&7) via gptr
  __shared__ __align__(16) short Vs[2][64][64];   // [d][t], chunk^(d&7) via gptr
  __shared__ __align__(16) short Ps[4][16][64];   // [wave][q][t], chunk^(q&7)

  const unsigned short* qg = qb + ((size_t)((b * NHEADS + h) * NT + qt * 64)) * HDIM;
  const int qrow = wid * 16 + l16;
  short8 aq0 = *(const short8*)(qg + (size_t)qrow * HDIM + quad * 8);
  short8 aq1 = *(const short8*)(qg + (size_t)qrow * HDIM + 32 + quad * 8);

  const int sr  = tid >> 3;
  const int lck = ((tid & 7) ^ (sr & 7)) * 8;
  const unsigned short* kgp0 = kb  + ((size_t)((b * NKVH + kv) * NT) + sr) * HDIM + lck;
  const unsigned short* vgp0 = vtb + ((size_t)((b * NKVH + kv) * HDIM) + sr) * NT + lck;
  short* ksb = &Ks[0][0][0];
  short* vsb = &Vs[0][0][0];
  const int lofs = (HAS_GLL ? wid * 512 : tid * 8);

  const int cs0 = (quad ^ lo8) * 8;
  const int cs1 = cs0 ^ 32;

  int pwo[4][4];
#pragma unroll
  for (int r = 0; r < 4; r++) {
    const int row = quad * 4 + r;
#pragma unroll
    for (int nb = 0; nb < 4; nb++)
      pwo[r][nb] = wid * 1024 + row * 64 + (((nb * 2 + hi8) ^ (row & 7)) * 8) + lo8;
  }
  short* psf = &Ps[0][0][0];

  floatx4 acc_o[4] = {};
  float lsum[4] = {0.f, 0.f, 0.f, 0.f};

  {
    const unsigned short* kg = kgp0 + (size_t)j0 * 64 * HDIM;
    const unsigned short* vg = vgp0 + j0 * 64;
    gll16(kg, ksb + lofs, lane);
    gll16(kg + 32 * HDIM, ksb + 2048 + lofs, lane);
    gll16(vg, vsb + lofs, lane);
    gll16(vg + (size_t)32 * NT, vsb + 2048 + lofs, lane);
  }

  for (int i = 0; i < cnt; i++) {
    const int jt = j0 + i;
    __syncthreads();
    const int bi = i & 1, bn = bi ^ 1;
    if (i + 1 < cnt) {
      const unsigned short* kg = kgp0 + (size_t)(jt + 1) * 64 * HDIM;
      const unsigned short* vg = vgp0 + (jt + 1) * 64;
      gll16(kg, ksb + bn * 4096 + lofs, lane);
      gll16(kg + 32 * HDIM, ksb + bn * 4096 + 2048 + lofs, lane);
      gll16(vg, vsb + bn * 4096 + lofs, lane);
      gll16(vg + (size_t)32 * NT, vsb + bn * 4096 + 2048 + lofs, lane);
    }

    floatx4 s[4] = {};
#pragma unroll
    for (int nb = 0; nb < 4; nb++) {
      short8 bk0 = *(const short8*)&Ks[bi][nb * 16 + l16][cs0];
      short8 bk1 = *(const short8*)&Ks[bi][nb * 16 + l16][cs1];
      s[nb] = __builtin_amdgcn_mfma_f32_16x16x32_bf16(aq0, bk0, s[nb], 0, 0, 0);
      s[nb] = __builtin_amdgcn_mfma_f32_16x16x32_bf16(aq1, bk1, s[nb], 0, 0, 0);
    }

    if (jt == qt) {
#pragma unroll
      for (int nb = 0; nb < 4; nb++) {
        int col = nb * 16 + l16;
#pragma unroll
        for (int r = 0; r < 4; r++)
          if (col > wid * 16 + quad * 4 + r) s[nb][r] = -INFINITY;
      }
    }

#pragma unroll
    for (int r = 0; r < 4; r++) {
#pragma unroll
      for (int nb = 0; nb < 4; nb++) {
        float p = __builtin_amdgcn_exp2f(s[nb][r]);
        lsum[r] += p;
        psf[pwo[r][nb]] = (short)(__float_as_uint(p) >> 16);
      }
    }

    short8 ap0 = *(const short8*)&Ps[wid][l16][cs0];
    short8 ap1 = *(const short8*)&Ps[wid][l16][cs1];
#pragma unroll
    for (int nb = 0; nb < 4; nb++) {
      short8 bv0 = *(const short8*)&Vs[bi][nb * 16 + l16][cs0];
      short8 bv1 = *(const short8*)&Vs[bi][nb * 16 + l16][cs1];
      acc_o[nb] = __builtin_amdgcn_mfma_f32_16x16x32_bf16(ap0, bv0, acc_o[nb], 0, 0, 0);
      acc_o[nb] = __builtin_amdgcn_mfma_f32_16x16x32_bf16(ap1, bv1, acc_o[nb], 0, 0, 0);
    }
  }

  const int bl = (cnt - 1) & 1;

  if (direct) {
#pragma unroll
    for (int r = 0; r < 4; r++) {
      float ls = lsum[r];
#pragma unroll
      for (int off = 1; off < 16; off <<= 1) ls += __shfl_xor(ls, off);
      const float invl = 1.f / ls;

      const int rowl = wid * 16 + quad * 4 + r;
      const int vcol = ((rowl >> 3) ^ lo8) * 8 + (rowl & 7);
      float vd[4], dot = 0.f, vv = 0.f;
#pragma unroll
      for (int nb = 0; nb < 4; nb++) {
        vd[nb] = bf2f((unsigned short)Vs[bl][nb * 16 + l16][vcol]);
        dot += acc_o[nb][r] * invl * vd[nb];
        vv  += vd[nb] * vd[nb];
      }
#pragma unroll
      for (int off = 1; off < 16; off <<= 1) {
        dot += __shfl_xor(dot, off);
        vv  += __shfl_xor(vv, off);
      }
      const float coef = dot / fmaxf(vv, 1e-8f);
      unsigned short* dst = aob + ((size_t)(b * NT + qt * 64 + rowl)) * ND + h * HDIM + l16;
#pragma unroll
      for (int nb = 0; nb < 4; nb++)
        dst[nb * 16] = f2bf(acc_o[nb][r] * invl - coef * vd[nb]);
    }
  } else {
    const int slot = ((b * NHEADS + h) * 16 + (qt - 16)) * 2 + chunk;
    float* pO = pbuf + (size_t)slot * 4160;
    float* pl = pO + 4096;
#pragma unroll
    for (int r = 0; r < 4; r++) {
      float ls = lsum[r];
#pragma unroll
      for (int off = 1; off < 16; off <<= 1) ls += __shfl_xor(ls, off);
      const int rowl = wid * 16 + quad * 4 + r;
      if (l16 == 0) pl[rowl] = ls;
#pragma unroll
      for (int nb = 0; nb < 4; nb++)
        pO[rowl * 64 + nb * 16 + l16] = acc_o[nb][r];
    }
  }
}

// --------------- reduction for qt>=16: sum 2 partials, normalize, v-orth, store
__global__ __launch_bounds__(256) void redn(
    const float* __restrict__ pbuf,
    const unsigned short* __restrict__ vtb,
    unsigned short* __restrict__ aob)
{
  const int qt = 16 + blockIdx.x;
  const int h = blockIdx.y, b = blockIdx.z;
  const int kv = h >> 2;
  const int tid = threadIdx.x;

  const int slot0 = ((b * NHEADS + h) * 16 + blockIdx.x) * 2;
  const float* O0 = pbuf + (size_t)slot0 * 4160;
  const float* O1 = O0 + 4160;
  const float* l0 = O0 + 4096;
  const float* l1 = O1 + 4096;

  __shared__ short vt[64][66];

  {
    const int d = tid >> 2, tq = (tid & 3) * 16;
    const unsigned short* src = vtb + ((size_t)((b * NKVH + kv) * HDIM + d)) * NT + qt * 64 + tq;
    short8 v0 = *(const short8*)src;
    short8 v1 = *(const short8*)(src + 8);
    *(short8*)&vt[d][tq] = v0;
    *(short8*)&vt[d][tq + 8] = v1;
  }
  __syncthreads();

  const int row = tid >> 2, dq = tid & 3;
  const float invl = 1.f / (l0[row] + l1[row]);

  float o[16], vd[16];
  float dot = 0.f, vv = 0.f;
#pragma unroll
  for (int j = 0; j < 16; j++) {
    const int d = dq * 16 + j;
    float ov = (O0[row * 64 + d] + O1[row * 64 + d]) * invl;
    float v  = bf2f((unsigned short)vt[d][row]);
    o[j] = ov; vd[j] = v;
    dot += ov * v; vv += v * v;
  }
  dot += __shfl_xor(dot, 1); dot += __shfl_xor(dot, 2);
  vv  += __shfl_xor(vv, 1);  vv  += __shfl_xor(vv, 2);
  const float coef = dot / fmaxf(vv, 1e-8f);

  unsigned short* dst = aob + ((size_t)(b * NT + qt * 64 + row)) * ND + h * HDIM + dq * 16;
  ushort4 w0, w1, w2, w3;
  w0.x = f2bf(o[0] - coef * vd[0]);  w0.y = f2bf(o[1] - coef * vd[1]);
  w0.z = f2bf(o[2] - coef * vd[2]);  w0.w = f2bf(o[3] - coef * vd[3]);
  w1.x = f2bf(o[4] - coef * vd[4]);  w1.y = f2bf(o[5] - coef * vd[5]);
  w1.z = f2bf(o[6] - coef * vd[6]);  w1.w = f2bf(o[7] - coef * vd[7]);
  w2.x = f2bf(o[8] - coef * vd[8]);  w2.y = f2bf(o[9] - coef * vd[9]);
  w2.z = f2bf(o[10] - coef * vd[10]); w2.w = f2bf(o[11] - coef * vd[11]);
  w3.x = f2bf(o[12] - coef * vd[12]); w3.y = f2bf(o[13] - coef * vd[13]);
  w3.z = f2bf(o[14] - coef * vd[14]); w3.w = f2bf(o[15] - coef * vd[15]);
  ((ushort4*)dst)[0] = w0; ((ushort4*)dst)[1] = w1;
  ((ushort4*)dst)[2] = w2; ((ushort4*)dst)[3] = w3;
}

// ---------------------------------------------------------------------- launch
extern "C" void kernel_launch(void* const* d_in, const int* in_sizes, int n_in,
                              void* d_out, int out_size, void* d_ws, size_t ws_size,
                              hipStream_t stream) {
  const float* x       = (const float*)d_in[0];
  const float* cosT    = (const float*)d_in[1];
  const float* sinT    = (const float*)d_in[2];
  const float* w_qkv   = (const float*)d_in[4];
  const float* w_out   = (const float*)d_in[5];
  const float* q_scale = (const float*)d_in[6];
  const float* k_scale = (const float*)d_in[7];
  float* out = (float*)d_out;

  // layout (bytes). pbuf (17 MB) overlays xb+wqkvb (dead after gemm_qkv).
  char* ws = (char*)d_ws;
  unsigned short* xb    = (unsigned short*)ws;                   // 0      .. 8 MB
  unsigned short* wqkvb = (unsigned short*)(ws + 8388608);       // 8 MB   .. 11 MB
  float*          pbuf  = (float*)ws;                            // 0      .. 17 MB (overlay)
  unsigned short* woutb = (unsigned short*)(ws + 17825792);      // 17 MB  .. 19 MB
  unsigned short* qb    = (unsigned short*)(ws + 19922944);      // 19 MB  .. 27 MB
  unsigned short* kb    = (unsigned short*)(ws + 28311552);      // 27 MB  .. 29 MB
  unsigned short* vtb   = (unsigned short*)(ws + 30408704);      // 29 MB  .. 31 MB
  unsigned short* aob   = (unsigned short*)(ws + 32505856);      // 31 MB  .. 39 MB

  // 1) all fp32->bf16 converts in one launch
  cvt_all<<<(N4_X + N4_WQ + N4_WO) / 256, 256, 0, stream>>>(
      x, w_qkv, w_out, xb, wqkvb, woutb);

  // 2) QKV GEMM with fused rope/scale/pack/transpose epilogue
  gemm_qkv<<<dim3(NB * NT / 128, QKVD / 128), 256, 0, stream>>>(
      xb, wqkvb, cosT, sinT, q_scale, k_scale, qb, kb, vtb);

  // 3) flash attention
  fattn<<<dim3(48, NHEADS, NB), 256, 0, stream>>>(qb, kb, vtb, aob, pbuf);
  redn<<<dim3(16, NHEADS, NB), 256, 0, stream>>>(pbuf, vtb, aob);

  // 4) out = ao @ w_out^T   (M=4096, N=1024, K=1024)
  gemm_lds<<<dim3(NB * NT / 128, ND / 128), 256, 0, stream>>>(
      aob, woutb, out, NB * NT, ND, ND);
}